// Round 8
// baseline (522.808 us; speedup 1.0000x reference)
//
#include <hip/hip_runtime.h>
#include <hip/hip_bf16.h>

typedef short bf16x8 __attribute__((ext_vector_type(8)));
typedef float f32x4 __attribute__((ext_vector_type(4)));

#define K_DIM 4096
#define N_DIM 16384
#define M_DIM 2048
#define STRIPE 16384                       // bytes per (tile128, kstep64) stripe in ws
#define TSTRIDE (64 * STRIPE)              // bytes per 128-row tile (1 MiB)
#define WSB_BYTES ((size_t)N_DIM * K_DIM * 2)   // 134217728
#define WSA_BYTES ((size_t)M_DIM * K_DIM * 2)   // 16777216

__device__ __forceinline__ unsigned f2bf(float f) {
    unsigned u = __builtin_bit_cast(unsigned, f);
    u += 0x7FFFu + ((u >> 16) & 1u);
    return u >> 16;   // RNE, inputs finite
}

// NVFP4 e2m1 nibble -> f32 (branchless), times scale
__device__ __forceinline__ float dec4(unsigned c, float s) {
    unsigned mag = c & 7u;
    unsigned u = (mag >= 2u) ? ((((mag >> 1) + 126u) << 23) | ((mag & 1u) << 22))
                             : (mag == 1u ? 0x3F000000u : 0u);
    u |= (c & 8u) << 28;   // sign
    return __builtin_bit_cast(float, u) * s;
}

__device__ __forceinline__ float gelu_tanh(float v) {
    float c = v + 0.044715f * v * v * v;
    float t = tanhf(0.7978845608028654f * c);
    return 0.5f * v * (1.0f + t);
}

// ---------------- Pass 1a: dequant W -> bf16, tiled + pre-swizzled (unchanged) ----------
__global__ __launch_bounds__(256) void dequant_w(const int* __restrict__ wp,
                                                 const float* __restrict__ wsc,
                                                 unsigned char* __restrict__ dst) {
    int t = blockIdx.x * 256 + threadIdx.x;      // 0 .. N*K/8-1
    int n = t >> 9;                              // K/8 = 512 chunks per row
    int ck = t & 511;
    int kstep = ck >> 3, s = ck & 7;
    int nt = n >> 7, r = n & 127;

    const int4 p4 = *reinterpret_cast<const int4*>(wp + (size_t)n * (K_DIM / 2) + kstep * 32 + s * 4);
    float scale = wsc[(size_t)n * (K_DIM / 32) + kstep * 2 + (s >> 2)];

    const int pv[4] = {p4.x, p4.y, p4.z, p4.w};
    unsigned o[8];
    #pragma unroll
    for (int j = 0; j < 4; ++j) {
        unsigned b = (unsigned)pv[j] & 255u;
        o[2 * j]     = f2bf(dec4(b & 15u, scale));
        o[2 * j + 1] = f2bf(dec4((b >> 4) & 15u, scale));
    }
    uint4 v;
    v.x = o[0] | (o[1] << 16);
    v.y = o[2] | (o[3] << 16);
    v.z = o[4] | (o[5] << 16);
    v.w = o[6] | (o[7] << 16);

    size_t off = (size_t)(nt * 64 + kstep) * STRIPE
               + (size_t)r * 128 + (size_t)((s ^ (r & 7)) << 4);
    *reinterpret_cast<uint4*>(dst + off) = v;
}

// ---------------- Pass 1b: x f32 -> bf16, tiled + pre-swizzled (unchanged) --------------
__global__ __launch_bounds__(256) void conv_x(const float* __restrict__ x,
                                              unsigned char* __restrict__ dst) {
    int t = blockIdx.x * 256 + threadIdx.x;      // 0 .. M*K/8-1
    int m = t >> 9;
    int ck = t & 511;
    int kstep = ck >> 3, s = ck & 7;
    int mt = m >> 7, r = m & 127;

    const float4* xp = reinterpret_cast<const float4*>(x + (size_t)m * K_DIM + kstep * 64 + s * 8);
    float4 a = xp[0], b = xp[1];
    uint4 v;
    v.x = f2bf(a.x) | (f2bf(a.y) << 16);
    v.y = f2bf(a.z) | (f2bf(a.w) << 16);
    v.z = f2bf(b.x) | (f2bf(b.y) << 16);
    v.w = f2bf(b.z) | (f2bf(b.w) << 16);

    size_t off = (size_t)(mt * 64 + kstep) * STRIPE
               + (size_t)r * 128 + (size_t)((s ^ (r & 7)) << 4);
    *reinterpret_cast<uint4*>(dst + off) = v;
}

// ---------------- Pass 2: 256^2 bf16 GEMM, BK=64 ring-2, both clusters reg-fed ----------
// 512 threads (8 waves, 2M x 4N), per-wave 128x64 = 8x4 frags of 16x16, K-tile = 64.
// LDS: 2 slots x 64 KiB. Slot: A halves at +0/+16K, B halves at +32K/+48K; each half
//   16 KiB = [kk:2][line L:64][slot p:8] x 16 B, line = row-pair {2L,2L+1},
//   p = ((row&1)<<2 | kq) ^ (L&7)  -- the r3-verified zero-conflict read layout.
// Per tile t (slot s=t&1): stage(t+1 -> s^1, 8 GLDS) issued first; read kk1 frags;
//   cluster kk0 (32 MFMA) from regs prefetched last tile; vmcnt(0)+barrier (stage
//   done -- covered by ~1500 cyc of reads+MFMA); prefetch t+1's kk0 frags from s^1;
//   cluster kk1 (32 MFMA) from the early-read regs; barrier.

__global__ __launch_bounds__(512, 2) void gemm_bf16_256(
    const unsigned char* __restrict__ wsA,
    const unsigned char* __restrict__ wsB,
    const float* __restrict__ bias,
    float* __restrict__ out)
{
    __shared__ unsigned char lds[131072];   // 2 slots x 64 KiB

    // XCD-chunked bijective swizzle
    int id = blockIdx.x;
    int wg = (id & 7) * 64 + (id >> 3);
    int MT = wg & 7;        // 0..7
    int NT = wg >> 3;       // 0..63

    const int tid  = threadIdx.x;
    const int lane = tid & 63;
    const int w    = tid >> 6;
    const int wm   = w >> 2;     // 0..1
    const int wn   = w & 3;      // 0..3
    const int fr   = lane & 15;  // fragment row
    const int fg   = lane >> 4;  // K-quarter within kk-half

    const unsigned char* gA = wsA + (size_t)(2 * MT) * TSTRIDE;
    const unsigned char* gB = wsB + (size_t)(2 * NT) * TSTRIDE;

    // ds_read byte addresses for kk=0 (kk=1 adds +8192, folded as constant)
    int addrA[8];
    #pragma unroll
    for (int mi = 0; mi < 8; ++mi) {
        int r = mi * 16 + fr;          // 0..127 within the wave's half
        int L = r >> 1;
        addrA[mi] = wm * 16384 + L * 128 + (((((r & 1) << 2) | fg) ^ (L & 7)) << 4);
    }
    int addrB[4];
    #pragma unroll
    for (int ni = 0; ni < 4; ++ni) {
        int row = wn * 64 + ni * 16 + fr;   // 0..255
        int H = row >> 7, r = row & 127;
        int L = r >> 1;
        addrB[ni] = 32768 + H * 16384 + L * 128
                  + (((((r & 1) << 2) | fg) ^ (L & 7)) << 4);
    }

    // staging src/dst offsets within one (stripe, half-buffer) pair
    int srcoff[2], dstoff[2];
    #pragma unroll
    for (int j = 0; j < 2; ++j) {
        int S = (w * 2 + j) * 64 + lane;     // 16-B slot index 0..1023
        int kkS = S >> 9;
        int L = (S >> 3) & 63;
        int p = S & 7;
        int hp = p ^ (L & 7);
        int row = 2 * L + (hp >> 2);
        int kq = hp & 3;
        srcoff[j] = row * 128 + ((((kkS << 2) | kq) ^ (row & 7)) << 4);
        dstoff[j] = (w * 2 + j) * 1024 + lane * 16;
    }

#define GLDS(SRC, DOFF) __builtin_amdgcn_global_load_lds(                          \
        (const __attribute__((address_space(1))) unsigned int*)(SRC),              \
        (__attribute__((address_space(3))) unsigned int*)(&lds[DOFF]), 16, 0, 0)

// stage one K-tile (stripe kt) into slot SS: 4 half-buffers x 2 chunks = 8 GLDS
#define STAGE_TILE(KT, SS) do {                                                    \
        size_t ko_ = (size_t)(KT) * STRIPE;                                        \
        _Pragma("unroll") for (int j = 0; j < 2; ++j) {                            \
            GLDS(gA + ko_ + srcoff[j],            ((SS) << 16) +         dstoff[j]); \
            GLDS(gA + TSTRIDE + ko_ + srcoff[j],  ((SS) << 16) + 16384 + dstoff[j]); \
            GLDS(gB + ko_ + srcoff[j],            ((SS) << 16) + 32768 + dstoff[j]); \
            GLDS(gB + TSTRIDE + ko_ + srcoff[j],  ((SS) << 16) + 49152 + dstoff[j]); \
        }                                                                          \
    } while (0)

// prefetch kk0 fragments of the tile in slot SS into pa/pb
#define READ_PF(SS) do {                                                           \
        const unsigned char* Lp_ = lds + ((SS) << 16);                             \
        _Pragma("unroll") for (int ni = 0; ni < 4; ++ni)                           \
            pb[ni] = *reinterpret_cast<const bf16x8*>(Lp_ + addrB[ni]);            \
        _Pragma("unroll") for (int mi = 0; mi < 8; ++mi)                           \
            pa[mi] = *reinterpret_cast<const bf16x8*>(Lp_ + addrA[mi]);            \
    } while (0)

    f32x4 acc[8][4];
    #pragma unroll
    for (int mi = 0; mi < 8; ++mi)
        #pragma unroll
        for (int ni = 0; ni < 4; ++ni)
            acc[mi][ni] = (f32x4){0.f, 0.f, 0.f, 0.f};

    bf16x8 pa[8], pb[4];     // kk0 fragments of the current tile (prefetched)

    // prologue: stage tile 0 -> slot 0; drain; prefetch its kk0 frags.
    STAGE_TILE(0, 0);
    asm volatile("s_waitcnt vmcnt(0)" ::: "memory");
    __builtin_amdgcn_sched_barrier(0);
    __builtin_amdgcn_s_barrier();
    __builtin_amdgcn_sched_barrier(0);
    READ_PF(0);

// DO_NXT: stage tile KT1 into SS^1 + prefetch its kk0 frags; LAST tile skips barriers.
#define TILE_BODY(SS, DO_NXT, KT1) do {                                            \
        const unsigned char* ls_ = lds + ((SS) << 16);                             \
        bf16x8 a1[8], b1[4];                                                       \
        if (DO_NXT) STAGE_TILE(KT1, (SS) ^ 1);                                     \
        _Pragma("unroll") for (int ni = 0; ni < 4; ++ni)                           \
            b1[ni] = *reinterpret_cast<const bf16x8*>(ls_ + addrB[ni] + 8192);     \
        _Pragma("unroll") for (int mi = 0; mi < 8; ++mi)                           \
            a1[mi] = *reinterpret_cast<const bf16x8*>(ls_ + addrA[mi] + 8192);     \
        __builtin_amdgcn_s_setprio(1);                                             \
        _Pragma("unroll") for (int mi = 0; mi < 8; ++mi)                           \
            _Pragma("unroll") for (int ni = 0; ni < 4; ++ni)                       \
                acc[mi][ni] = __builtin_amdgcn_mfma_f32_16x16x32_bf16(             \
                    pa[mi], pb[ni], acc[mi][ni], 0, 0, 0);                         \
        __builtin_amdgcn_s_setprio(0);                                             \
        if (DO_NXT) {                                                              \
            asm volatile("s_waitcnt vmcnt(0)" ::: "memory");                       \
            __builtin_amdgcn_sched_barrier(0);                                     \
            __builtin_amdgcn_s_barrier();                                          \
            __builtin_amdgcn_sched_barrier(0);                                     \
            READ_PF((SS) ^ 1);                                                     \
        }                                                                          \
        __builtin_amdgcn_s_setprio(1);                                             \
        _Pragma("unroll") for (int mi = 0; mi < 8; ++mi)                           \
            _Pragma("unroll") for (int ni = 0; ni < 4; ++ni)                       \
                acc[mi][ni] = __builtin_amdgcn_mfma_f32_16x16x32_bf16(             \
                    a1[mi], b1[ni], acc[mi][ni], 0, 0, 0);                         \
        __builtin_amdgcn_s_setprio(0);                                             \
        if (DO_NXT) {                                                              \
            __builtin_amdgcn_sched_barrier(0);                                     \
            __builtin_amdgcn_s_barrier();                                          \
            __builtin_amdgcn_sched_barrier(0);                                     \
        }                                                                          \
    } while (0)

    // 64 K-tiles: pairs (slot0, slot1); t=62 stages 63; t=63 computes only.
    for (int tp = 0; tp < 31; ++tp) {
        TILE_BODY(0, 1, 2 * tp + 1);
        TILE_BODY(1, 1, 2 * tp + 2);
    }
    TILE_BODY(0, 1, 63);
    TILE_BODY(1, 0, 0);

    // epilogue: bias + tanh-GELU, f32 stores (16x16 C/D: col=lane&15, row=(lane>>4)*4+q)
    const int bm0 = MT * 256, bn0 = NT * 256;
    #pragma unroll
    for (int mi = 0; mi < 8; ++mi) {
        int row = bm0 + wm * 128 + mi * 16 + fg * 4;
        #pragma unroll
        for (int ni = 0; ni < 4; ++ni) {
            int col = bn0 + wn * 64 + ni * 16 + fr;
            float bv = bias[col];
            float* op = out + (size_t)row * N_DIM + col;
            #pragma unroll
            for (int q = 0; q < 4; ++q) {
                float v = acc[mi][ni][q] + bv;
                op[(size_t)q * N_DIM] = gelu_tanh(v);
            }
        }
    }
#undef TILE_BODY
#undef READ_PF
#undef STAGE_TILE
#undef GLDS
}

// ---------------- Fallback: round-1 fused kernel (used only if ws too small) ------------
__global__ __launch_bounds__(256, 2) void nvfp4_gemm(
    const float* __restrict__ x,
    const int*   __restrict__ wp,
    const float* __restrict__ wscale,
    const float* __restrict__ bias,
    float* __restrict__ out)
{
    __shared__ uint4  lsA[128 * 8];
    __shared__ uint4  lsB[128 * 8];
    __shared__ float2 lut[256];

    const int tid = threadIdx.x;
    {
        static const float dectab[16] = {0.f, 0.5f, 1.f, 1.5f, 2.f, 3.f, 4.f, 6.f,
                                         -0.f,-0.5f,-1.f,-1.5f,-2.f,-3.f,-4.f,-6.f};
        lut[tid] = make_float2(dectab[tid & 15], dectab[(tid >> 4) & 15]);
    }

    const int bn0 = blockIdx.x * 128;
    const int bm0 = blockIdx.y * 128;
    const int r = tid >> 1;
    const int h = tid & 1;

    const float4* xp = reinterpret_cast<const float4*>(x + (size_t)(bm0 + r) * K_DIM) + h * 8;
    const uint4*  bp = reinterpret_cast<const uint4*>(wp + (size_t)(bn0 + r) * (K_DIM / 2)) + h * 4;
    const float*  sp = wscale + (size_t)(bn0 + r) * (K_DIM / 32) + h;

    float4 ax[8];
    uint4  bx[4];
    float  scale;
    #pragma unroll
    for (int j = 0; j < 8; ++j) ax[j] = xp[j];
    #pragma unroll
    for (int q = 0; q < 4; ++q) bx[q] = bp[q];
    scale = sp[0];

    f32x4 acc[4][4];
    #pragma unroll
    for (int mi = 0; mi < 4; ++mi)
        #pragma unroll
        for (int ni = 0; ni < 4; ++ni)
            acc[mi][ni] = (f32x4){0.f, 0.f, 0.f, 0.f};

    const int lane = tid & 63;
    const int wid  = tid >> 6;
    const int wm0  = (wid >> 1) * 64;
    const int wn0  = (wid & 1) * 64;
    const int fr   = lane & 15;
    const int fg   = lane >> 4;

    __syncthreads();

    for (int kt = 0; kt < 64; ++kt) {
        #pragma unroll
        for (int j = 0; j < 4; ++j) {
            float4 f0 = ax[2 * j], f1 = ax[2 * j + 1];
            uint4 v;
            v.x = f2bf(f0.x) | (f2bf(f0.y) << 16);
            v.y = f2bf(f0.z) | (f2bf(f0.w) << 16);
            v.z = f2bf(f1.x) | (f2bf(f1.y) << 16);
            v.w = f2bf(f1.z) | (f2bf(f1.w) << 16);
            lsA[(r * 8 + h * 4 + j) ^ (r & 7)] = v;
        }
        #pragma unroll
        for (int q = 0; q < 4; ++q) {
            uint4 p = bx[q];
            float2 d0 = lut[p.x & 255];
            float2 d1 = lut[p.y & 255];
            float2 d2 = lut[p.z & 255];
            float2 d3 = lut[p.w & 255];
            uint4 v;
            v.x = f2bf(d0.x * scale) | (f2bf(d0.y * scale) << 16);
            v.y = f2bf(d1.x * scale) | (f2bf(d1.y * scale) << 16);
            v.z = f2bf(d2.x * scale) | (f2bf(d2.y * scale) << 16);
            v.w = f2bf(d3.x * scale) | (f2bf(d3.y * scale) << 16);
            lsB[(r * 8 + h * 4 + q) ^ (r & 7)] = v;
        }
        __syncthreads();

        if (kt + 1 < 64) {
            #pragma unroll
            for (int j = 0; j < 8; ++j) ax[j] = xp[(kt + 1) * 16 + j];
            #pragma unroll
            for (int q = 0; q < 4; ++q) bx[q] = bp[(kt + 1) * 8 + q];
            scale = sp[(kt + 1) * 2];
        }

        #pragma unroll
        for (int kk = 0; kk < 2; ++kk) {
            bf16x8 af[4], bfr[4];
            #pragma unroll
            for (int mi = 0; mi < 4; ++mi) {
                int row = wm0 + mi * 16 + fr;
                af[mi] = __builtin_bit_cast(bf16x8, lsA[(row * 8 + kk * 4 + fg) ^ (row & 7)]);
            }
            #pragma unroll
            for (int ni = 0; ni < 4; ++ni) {
                int row = wn0 + ni * 16 + fr;
                bfr[ni] = __builtin_bit_cast(bf16x8, lsB[(row * 8 + kk * 4 + fg) ^ (row & 7)]);
            }
            #pragma unroll
            for (int mi = 0; mi < 4; ++mi)
                #pragma unroll
                for (int ni = 0; ni < 4; ++ni)
                    acc[mi][ni] = __builtin_amdgcn_mfma_f32_16x16x32_bf16(
                        af[mi], bfr[ni], acc[mi][ni], 0, 0, 0);
        }
        __syncthreads();
    }

    #pragma unroll
    for (int mi = 0; mi < 4; ++mi) {
        int row = bm0 + wm0 + mi * 16 + fg * 4;
        #pragma unroll
        for (int ni = 0; ni < 4; ++ni) {
            int col = bn0 + wn0 + ni * 16 + fr;
            float bv = bias[col];
            float* op = out + (size_t)row * N_DIM + col;
            #pragma unroll
            for (int q = 0; q < 4; ++q) {
                float v = acc[mi][ni][q] + bv;
                op[(size_t)q * N_DIM] = gelu_tanh(v);
            }
        }
    }
}

extern "C" void kernel_launch(void* const* d_in, const int* in_sizes, int n_in,
                              void* d_out, int out_size, void* d_ws, size_t ws_size,
                              hipStream_t stream) {
    const float* x    = (const float*)d_in[0];
    const int*   wp   = (const int*)d_in[1];
    const float* wsc  = (const float*)d_in[2];
    const float* bias = (const float*)d_in[3];
    float*       out  = (float*)d_out;
    (void)in_sizes; (void)n_in; (void)out_size;

    if (ws_size >= WSB_BYTES + WSA_BYTES) {
        unsigned char* wsB = (unsigned char*)d_ws;
        unsigned char* wsA = wsB + WSB_BYTES;
        dequant_w<<<(N_DIM * (K_DIM / 8)) / 256, 256, 0, stream>>>(wp, wsc, wsB);
        conv_x<<<(M_DIM * (K_DIM / 8)) / 256, 256, 0, stream>>>(x, wsA);
        gemm_bf16_256<<<(M_DIM / 256) * (N_DIM / 256), 512, 0, stream>>>(wsA, wsB, bias, out);
    } else {
        dim3 grid(N_DIM / 128, M_DIM / 128);
        nvfp4_gemm<<<grid, 256, 0, stream>>>(x, wp, wsc, bias, out);
    }
}

// Round 9
// 328.157 us; speedup vs baseline: 1.5932x; 1.5932x over previous
//
#include <hip/hip_runtime.h>
#include <hip/hip_bf16.h>

typedef short bf16x8 __attribute__((ext_vector_type(8)));
typedef float f32x4 __attribute__((ext_vector_type(4)));

#define K_DIM 4096
#define N_DIM 16384
#define M_DIM 2048
#define STRIPE 16384                       // bytes per (tile128, kstep64) stripe in ws
#define TSTRIDE (64 * STRIPE)              // bytes per 128-row tile (1 MiB)
#define WSB_BYTES ((size_t)N_DIM * K_DIM * 2)   // 134217728
#define WSA_BYTES ((size_t)M_DIM * K_DIM * 2)   // 16777216

__device__ __forceinline__ unsigned f2bf(float f) {
    unsigned u = __builtin_bit_cast(unsigned, f);
    u += 0x7FFFu + ((u >> 16) & 1u);
    return u >> 16;   // RNE, inputs finite
}

// NVFP4 e2m1 nibble -> f32 (branchless), times scale
__device__ __forceinline__ float dec4(unsigned c, float s) {
    unsigned mag = c & 7u;
    unsigned u = (mag >= 2u) ? ((((mag >> 1) + 126u) << 23) | ((mag & 1u) << 22))
                             : (mag == 1u ? 0x3F000000u : 0u);
    u |= (c & 8u) << 28;   // sign
    return __builtin_bit_cast(float, u) * s;
}

__device__ __forceinline__ float gelu_tanh(float v) {
    float c = v + 0.044715f * v * v * v;
    float t = tanhf(0.7978845608028654f * c);
    return 0.5f * v * (1.0f + t);
}

// ---------------- Pass 1a: dequant W -> bf16, tiled + pre-swizzled (unchanged) ----------
__global__ __launch_bounds__(256) void dequant_w(const int* __restrict__ wp,
                                                 const float* __restrict__ wsc,
                                                 unsigned char* __restrict__ dst) {
    int t = blockIdx.x * 256 + threadIdx.x;      // 0 .. N*K/8-1
    int n = t >> 9;                              // K/8 = 512 chunks per row
    int ck = t & 511;
    int kstep = ck >> 3, s = ck & 7;
    int nt = n >> 7, r = n & 127;

    const int4 p4 = *reinterpret_cast<const int4*>(wp + (size_t)n * (K_DIM / 2) + kstep * 32 + s * 4);
    float scale = wsc[(size_t)n * (K_DIM / 32) + kstep * 2 + (s >> 2)];

    const int pv[4] = {p4.x, p4.y, p4.z, p4.w};
    unsigned o[8];
    #pragma unroll
    for (int j = 0; j < 4; ++j) {
        unsigned b = (unsigned)pv[j] & 255u;
        o[2 * j]     = f2bf(dec4(b & 15u, scale));
        o[2 * j + 1] = f2bf(dec4((b >> 4) & 15u, scale));
    }
    uint4 v;
    v.x = o[0] | (o[1] << 16);
    v.y = o[2] | (o[3] << 16);
    v.z = o[4] | (o[5] << 16);
    v.w = o[6] | (o[7] << 16);

    size_t off = (size_t)(nt * 64 + kstep) * STRIPE
               + (size_t)r * 128 + (size_t)((s ^ (r & 7)) << 4);
    *reinterpret_cast<uint4*>(dst + off) = v;
}

// ---------------- Pass 1b: x f32 -> bf16, tiled + pre-swizzled (unchanged) --------------
__global__ __launch_bounds__(256) void conv_x(const float* __restrict__ x,
                                              unsigned char* __restrict__ dst) {
    int t = blockIdx.x * 256 + threadIdx.x;      // 0 .. M*K/8-1
    int m = t >> 9;
    int ck = t & 511;
    int kstep = ck >> 3, s = ck & 7;
    int mt = m >> 7, r = m & 127;

    const float4* xp = reinterpret_cast<const float4*>(x + (size_t)m * K_DIM + kstep * 64 + s * 8);
    float4 a = xp[0], b = xp[1];
    uint4 v;
    v.x = f2bf(a.x) | (f2bf(a.y) << 16);
    v.y = f2bf(a.z) | (f2bf(a.w) << 16);
    v.z = f2bf(b.x) | (f2bf(b.y) << 16);
    v.w = f2bf(b.z) | (f2bf(b.w) << 16);

    size_t off = (size_t)(mt * 64 + kstep) * STRIPE
               + (size_t)r * 128 + (size_t)((s ^ (r & 7)) << 4);
    *reinterpret_cast<uint4*>(dst + off) = v;
}

// ---------------- Pass 2: 256^2 bf16 GEMM, ring-4 (r6 memory logic), 2-phase body -------
// BK=32, 512 threads (8 waves, 2M x 4N), per-wave 128x64 = 8x4 frags of 16x16.
// Memory logic byte-identical to round-6 (283us verified): ring-4 slots, stage(t+3)
// during tile t, vmcnt(4) cadence, zero-conflict r3 layout, reg-prefetch of tile t+1's
// A[0..3]+B[0..3] during tile t.  NEW (m201 phase discipline): each 16-MFMA cluster is
// fenced by s_barrier pairs, with ds_reads/stages issued between fences -- aligns the
// 8 waves into {LDS-batch | MFMA-batch} roles so setprio has something to arbitrate.

__global__ __launch_bounds__(512, 2) void gemm_bf16_256(
    const unsigned char* __restrict__ wsA,
    const unsigned char* __restrict__ wsB,
    const float* __restrict__ bias,
    float* __restrict__ out)
{
    __shared__ unsigned char lds[131072];   // [0,64K) = A slots, [64K,128K) = B slots

    // XCD-chunked bijective swizzle
    int id = blockIdx.x;
    int wg = (id & 7) * 64 + (id >> 3);
    int MT = wg & 7;        // 0..7
    int NT = wg >> 3;       // 0..63

    const int tid  = threadIdx.x;
    const int lane = tid & 63;
    const int w    = tid >> 6;
    const int wm   = w >> 2;     // 0..1
    const int wn   = w & 3;      // 0..3
    const int fr   = lane & 15;  // fragment row
    const int fg   = lane >> 4;  // K-quarter 0..3

    const unsigned char* gA = wsA + (size_t)(2 * MT) * TSTRIDE;
    const unsigned char* gB = wsB + (size_t)(2 * NT) * TSTRIDE;

    // ds_read byte addresses (round-3 formulas, zero-conflict verified)
    int addrA[8];
    #pragma unroll
    for (int mi = 0; mi < 8; ++mi) {
        int row = wm * 128 + mi * 16 + fr;
        int L = row >> 1;
        addrA[mi] = L * 128 + (((((row & 1) << 2) | fg) ^ (L & 7)) << 4);
    }
    int addrB[4];
    #pragma unroll
    for (int ni = 0; ni < 4; ++ni) {
        int row = wn * 64 + ni * 16 + fr;
        int L = row >> 1;
        addrB[ni] = L * 128 + (((((row & 1) << 2) | fg) ^ (L & 7)) << 4);
    }

    // staging source offsets (round-3 version, matches the read layout above)
    int offST[2][2];
    #pragma unroll
    for (int j = 0; j < 2; ++j) {
        int c = w * 2 + j;
        int L = c * 8 + (lane >> 3);
        int p = lane & 7;
        int sl = p ^ (L & 7);
        int h = sl >> 2, fgs = sl & 3;
        int row = 2 * L + h;
        #pragma unroll
        for (int kb = 0; kb < 2; ++kb)
            offST[j][kb] = (row >> 7) * TSTRIDE + (row & 127) * 128
                         + ((((kb << 2) | fgs) ^ (row & 7)) << 4);
    }

#define GLDS(SRC, DOFF) __builtin_amdgcn_global_load_lds(                          \
        (const __attribute__((address_space(1))) unsigned int*)(SRC),              \
        (__attribute__((address_space(3))) unsigned int*)(&lds[DOFF]), 16, 0, 0)

#define STAGE_A(KSOFF, KB, SLOT) do {                                              \
        GLDS(gA + (KSOFF) + offST[0][KB], ((SLOT) << 14) + (w * 2 + 0) * 1024);    \
        GLDS(gA + (KSOFF) + offST[1][KB], ((SLOT) << 14) + (w * 2 + 1) * 1024);    \
    } while (0)
#define STAGE_B(KSOFF, KB, SLOT) do {                                              \
        GLDS(gB + (KSOFF) + offST[0][KB], 65536 + ((SLOT) << 14) + (w * 2 + 0) * 1024); \
        GLDS(gB + (KSOFF) + offST[1][KB], 65536 + ((SLOT) << 14) + (w * 2 + 1) * 1024); \
    } while (0)

// prefetch a tile's B[0..3] + A[0..3] fragments into named register arrays
#define READ_PF(PA, PB, SLOT) do {                                                 \
        const unsigned char* La_ = lds + ((SLOT) << 14);                           \
        const unsigned char* Lb_ = lds + 65536 + ((SLOT) << 14);                   \
        _Pragma("unroll") for (int ni = 0; ni < 4; ++ni)                           \
            PB[ni] = *reinterpret_cast<const bf16x8*>(Lb_ + addrB[ni]);            \
        _Pragma("unroll") for (int mi = 0; mi < 4; ++mi)                           \
            PA[mi] = *reinterpret_cast<const bf16x8*>(La_ + addrA[mi]);            \
    } while (0)

#define FENCE() do {                                                               \
        __builtin_amdgcn_sched_barrier(0);                                         \
        __builtin_amdgcn_s_barrier();                                              \
        __builtin_amdgcn_sched_barrier(0);                                         \
    } while (0)

    f32x4 acc[8][4];
    #pragma unroll
    for (int mi = 0; mi < 8; ++mi)
        #pragma unroll
        for (int ni = 0; ni < 4; ++ni)
            acc[mi][ni] = (f32x4){0.f, 0.f, 0.f, 0.f};

    bf16x8 pa0[4], pb0[4], pa1[4], pb1[4];   // double-buffered prefetch fragments

    // prologue: stage tiles 0,1,2 into slots 0,1,2; wait tiles 0+1 (vmcnt(4)).
    STAGE_A(0, 0, 0);        STAGE_B(0, 0, 0);
    STAGE_A(0, 1, 1);        STAGE_B(0, 1, 1);
    STAGE_A(STRIPE, 0, 2);   STAGE_B(STRIPE, 0, 2);
    asm volatile("s_waitcnt vmcnt(4)" ::: "memory");
    FENCE();
    READ_PF(pa0, pb0, 0);

// one K-tile, two barrier-fenced phases (memory ops identical to round-6):
//  P1: stage_A(t+3); ds ka=A(t)[4..7]; FENCE; 16 MFMA (prefetched pa/pb); FENCE
//  P2: stage_B(t+3); READ_PF(t+1);     FENCE; 16 MFMA (ka/pb);  then vmcnt+boundary
#define TILE_BODY(RSLOT, NSLOT, PA, PB, NPA, NPB, DO_STG, STKS, STKB, SSLOT, DO_PF, VMN) do { \
        const unsigned char* la = lds + ((RSLOT) << 14);                           \
        bf16x8 ka[4];                                                              \
        if (DO_STG) STAGE_A(STKS, STKB, SSLOT);                                    \
        _Pragma("unroll") for (int mi = 0; mi < 4; ++mi)                           \
            ka[mi] = *reinterpret_cast<const bf16x8*>(la + addrA[4 + mi]);         \
        FENCE();                                                                   \
        __builtin_amdgcn_s_setprio(1);                                             \
        _Pragma("unroll") for (int mi = 0; mi < 4; ++mi)                           \
            _Pragma("unroll") for (int ni = 0; ni < 4; ++ni)                       \
                acc[mi][ni] = __builtin_amdgcn_mfma_f32_16x16x32_bf16(             \
                    PA[mi], PB[ni], acc[mi][ni], 0, 0, 0);                         \
        __builtin_amdgcn_s_setprio(0);                                             \
        FENCE();                                                                   \
        if (DO_STG) STAGE_B(STKS, STKB, SSLOT);                                    \
        if (DO_PF) READ_PF(NPA, NPB, NSLOT);                                       \
        FENCE();                                                                   \
        __builtin_amdgcn_s_setprio(1);                                             \
        _Pragma("unroll") for (int mi = 0; mi < 4; ++mi)                           \
            _Pragma("unroll") for (int ni = 0; ni < 4; ++ni)                       \
                acc[4 + mi][ni] = __builtin_amdgcn_mfma_f32_16x16x32_bf16(         \
                    ka[mi], PB[ni], acc[4 + mi][ni], 0, 0, 0);                     \
        __builtin_amdgcn_s_setprio(0);                                             \
        if ((VMN) >= 0) {                                                          \
            if ((VMN) == 4)      asm volatile("s_waitcnt vmcnt(4)" ::: "memory");  \
            else                 asm volatile("s_waitcnt vmcnt(0)" ::: "memory");  \
            FENCE();                                                               \
        }                                                                          \
    } while (0)

    // main loop: tiles t = 2tp, 2tp+1 for tp = 0..61; stage tile t+3; vmcnt(4) cadence.
    for (int tp = 0; tp < 62; ++tp) {
        const int scur = (tp & 1) << 1;              // slot of tile 2tp (0 or 2)
        const int ks1 = (tp + 1) * STRIPE;           // stage tile 2tp+3 (kb=1)
        const int ks2 = (tp + 2) * STRIPE;           // stage tile 2tp+4 (kb=0)
        TILE_BODY(scur,     scur ^ 1, pa0, pb0, pa1, pb1, 1, ks1, 1, scur ^ 3, 1, 4);
        TILE_BODY(scur ^ 1, scur ^ 2, pa1, pb1, pa0, pb0, 1, ks2, 0, scur,     1, 4);
    }
    // tail: tiles 124..127 in slots 0..3; stage only 127; drain 4 -> 0 -> 0.
    TILE_BODY(0, 1, pa0, pb0, pa1, pb1, 1, 63 * STRIPE, 1, 3, 1, 4);
    TILE_BODY(1, 2, pa1, pb1, pa0, pb0, 0, 0, 0, 0, 1, 0);
    TILE_BODY(2, 3, pa0, pb0, pa1, pb1, 0, 0, 0, 0, 1, 0);
    TILE_BODY(3, 0, pa1, pb1, pa0, pb0, 0, 0, 0, 0, 0, -1);

    // epilogue: bias + tanh-GELU, f32 stores (16x16 C/D layout: col=lane&15,
    // row = (lane>>4)*4 + reg).
    const int bm0 = MT * 256, bn0 = NT * 256;
    #pragma unroll
    for (int mi = 0; mi < 8; ++mi) {
        int row = bm0 + wm * 128 + mi * 16 + fg * 4;
        #pragma unroll
        for (int ni = 0; ni < 4; ++ni) {
            int col = bn0 + wn * 64 + ni * 16 + fr;
            float bv = bias[col];
            float* op = out + (size_t)row * N_DIM + col;
            #pragma unroll
            for (int q = 0; q < 4; ++q) {
                float v = acc[mi][ni][q] + bv;
                op[(size_t)q * N_DIM] = gelu_tanh(v);
            }
        }
    }
#undef TILE_BODY
#undef FENCE
#undef READ_PF
#undef STAGE_A
#undef STAGE_B
#undef GLDS
}

// ---------------- Fallback: round-1 fused kernel (used only if ws too small) ------------
__global__ __launch_bounds__(256, 2) void nvfp4_gemm(
    const float* __restrict__ x,
    const int*   __restrict__ wp,
    const float* __restrict__ wscale,
    const float* __restrict__ bias,
    float* __restrict__ out)
{
    __shared__ uint4  lsA[128 * 8];
    __shared__ uint4  lsB[128 * 8];
    __shared__ float2 lut[256];

    const int tid = threadIdx.x;
    {
        static const float dectab[16] = {0.f, 0.5f, 1.f, 1.5f, 2.f, 3.f, 4.f, 6.f,
                                         -0.f,-0.5f,-1.f,-1.5f,-2.f,-3.f,-4.f,-6.f};
        lut[tid] = make_float2(dectab[tid & 15], dectab[(tid >> 4) & 15]);
    }

    const int bn0 = blockIdx.x * 128;
    const int bm0 = blockIdx.y * 128;
    const int r = tid >> 1;
    const int h = tid & 1;

    const float4* xp = reinterpret_cast<const float4*>(x + (size_t)(bm0 + r) * K_DIM) + h * 8;
    const uint4*  bp = reinterpret_cast<const uint4*>(wp + (size_t)(bn0 + r) * (K_DIM / 2)) + h * 4;
    const float*  sp = wscale + (size_t)(bn0 + r) * (K_DIM / 32) + h;

    float4 ax[8];
    uint4  bx[4];
    float  scale;
    #pragma unroll
    for (int j = 0; j < 8; ++j) ax[j] = xp[j];
    #pragma unroll
    for (int q = 0; q < 4; ++q) bx[q] = bp[q];
    scale = sp[0];

    f32x4 acc[4][4];
    #pragma unroll
    for (int mi = 0; mi < 4; ++mi)
        #pragma unroll
        for (int ni = 0; ni < 4; ++ni)
            acc[mi][ni] = (f32x4){0.f, 0.f, 0.f, 0.f};

    const int lane = tid & 63;
    const int wid  = tid >> 6;
    const int wm0  = (wid >> 1) * 64;
    const int wn0  = (wid & 1) * 64;
    const int fr   = lane & 15;
    const int fg   = lane >> 4;

    __syncthreads();

    for (int kt = 0; kt < 64; ++kt) {
        #pragma unroll
        for (int j = 0; j < 4; ++j) {
            float4 f0 = ax[2 * j], f1 = ax[2 * j + 1];
            uint4 v;
            v.x = f2bf(f0.x) | (f2bf(f0.y) << 16);
            v.y = f2bf(f0.z) | (f2bf(f0.w) << 16);
            v.z = f2bf(f1.x) | (f2bf(f1.y) << 16);
            v.w = f2bf(f1.z) | (f2bf(f1.w) << 16);
            lsA[(r * 8 + h * 4 + j) ^ (r & 7)] = v;
        }
        #pragma unroll
        for (int q = 0; q < 4; ++q) {
            uint4 p = bx[q];
            float2 d0 = lut[p.x & 255];
            float2 d1 = lut[p.y & 255];
            float2 d2 = lut[p.z & 255];
            float2 d3 = lut[p.w & 255];
            uint4 v;
            v.x = f2bf(d0.x * scale) | (f2bf(d0.y * scale) << 16);
            v.y = f2bf(d1.x * scale) | (f2bf(d1.y * scale) << 16);
            v.z = f2bf(d2.x * scale) | (f2bf(d2.y * scale) << 16);
            v.w = f2bf(d3.x * scale) | (f2bf(d3.y * scale) << 16);
            lsB[(r * 8 + h * 4 + q) ^ (r & 7)] = v;
        }
        __syncthreads();

        if (kt + 1 < 64) {
            #pragma unroll
            for (int j = 0; j < 8; ++j) ax[j] = xp[(kt + 1) * 16 + j];
            #pragma unroll
            for (int q = 0; q < 4; ++q) bx[q] = bp[(kt + 1) * 8 + q];
            scale = sp[(kt + 1) * 2];
        }

        #pragma unroll
        for (int kk = 0; kk < 2; ++kk) {
            bf16x8 af[4], bfr[4];
            #pragma unroll
            for (int mi = 0; mi < 4; ++mi) {
                int row = wm0 + mi * 16 + fr;
                af[mi] = __builtin_bit_cast(bf16x8, lsA[(row * 8 + kk * 4 + fg) ^ (row & 7)]);
            }
            #pragma unroll
            for (int ni = 0; ni < 4; ++ni) {
                int row = wn0 + ni * 16 + fr;
                bfr[ni] = __builtin_bit_cast(bf16x8, lsB[(row * 8 + kk * 4 + fg) ^ (row & 7)]);
            }
            #pragma unroll
            for (int mi = 0; mi < 4; ++mi)
                #pragma unroll
                for (int ni = 0; ni < 4; ++ni)
                    acc[mi][ni] = __builtin_amdgcn_mfma_f32_16x16x32_bf16(
                        af[mi], bfr[ni], acc[mi][ni], 0, 0, 0);
        }
        __syncthreads();
    }

    #pragma unroll
    for (int mi = 0; mi < 4; ++mi) {
        int row = bm0 + wm0 + mi * 16 + fg * 4;
        #pragma unroll
        for (int ni = 0; ni < 4; ++ni) {
            int col = bn0 + wn0 + ni * 16 + fr;
            float bv = bias[col];
            float* op = out + (size_t)row * N_DIM + col;
            #pragma unroll
            for (int q = 0; q < 4; ++q) {
                float v = acc[mi][ni][q] + bv;
                op[(size_t)q * N_DIM] = gelu_tanh(v);
            }
        }
    }
}

extern "C" void kernel_launch(void* const* d_in, const int* in_sizes, int n_in,
                              void* d_out, int out_size, void* d_ws, size_t ws_size,
                              hipStream_t stream) {
    const float* x    = (const float*)d_in[0];
    const int*   wp   = (const int*)d_in[1];
    const float* wsc  = (const float*)d_in[2];
    const float* bias = (const float*)d_in[3];
    float*       out  = (float*)d_out;
    (void)in_sizes; (void)n_in; (void)out_size;

    if (ws_size >= WSB_BYTES + WSA_BYTES) {
        unsigned char* wsB = (unsigned char*)d_ws;
        unsigned char* wsA = wsB + WSB_BYTES;
        dequant_w<<<(N_DIM * (K_DIM / 8)) / 256, 256, 0, stream>>>(wp, wsc, wsB);
        conv_x<<<(M_DIM * (K_DIM / 8)) / 256, 256, 0, stream>>>(x, wsA);
        gemm_bf16_256<<<(M_DIM / 256) * (N_DIM / 256), 512, 0, stream>>>(wsA, wsB, bias, out);
    } else {
        dim3 grid(N_DIM / 128, M_DIM / 128);
        nvfp4_gemm<<<grid, 256, 0, stream>>>(x, wp, wsc, bias, out);
    }
}

// Round 10
// 325.883 us; speedup vs baseline: 1.6043x; 1.0070x over previous
//
#include <hip/hip_runtime.h>
#include <hip/hip_bf16.h>

typedef short bf16x8 __attribute__((ext_vector_type(8)));
typedef float f32x4 __attribute__((ext_vector_type(4)));

#define K_DIM 4096
#define N_DIM 16384
#define M_DIM 2048
#define STRIPE 16384                       // bytes per (tile128, kstep64) stripe in ws
#define TSTRIDE (64 * STRIPE)              // bytes per 128-row tile (1 MiB)
#define WSB_BYTES ((size_t)N_DIM * K_DIM * 2)   // 134217728
#define WSA_BYTES ((size_t)M_DIM * K_DIM * 2)   // 16777216
#define W_BLOCKS 32768                     // dequant blocks in merged prep
#define X_BLOCKS 4096                      // conv blocks in merged prep

__device__ __forceinline__ unsigned f2bf(float f) {
    unsigned u = __builtin_bit_cast(unsigned, f);
    u += 0x7FFFu + ((u >> 16) & 1u);
    return u >> 16;   // RNE, inputs finite
}

// NVFP4 e2m1 nibble -> f32 (branchless), times scale
__device__ __forceinline__ float dec4(unsigned c, float s) {
    unsigned mag = c & 7u;
    unsigned u = (mag >= 2u) ? ((((mag >> 1) + 126u) << 23) | ((mag & 1u) << 22))
                             : (mag == 1u ? 0x3F000000u : 0u);
    u |= (c & 8u) << 28;   // sign
    return __builtin_bit_cast(float, u) * s;
}

__device__ __forceinline__ float gelu_tanh(float v) {
    float c = v + 0.044715f * v * v * v;
    float t = tanhf(0.7978845608028654f * c);
    return 0.5f * v * (1.0f + t);
}

// ---------------- Pass 1 (merged): dequant W -> bf16  AND  x f32 -> bf16 ----------------
// Both outputs tiled + pre-swizzled exactly as rounds 2-6 (verified).
__global__ __launch_bounds__(256) void prep(const int* __restrict__ wp,
                                            const float* __restrict__ wsc,
                                            const float* __restrict__ x,
                                            unsigned char* __restrict__ dstW,
                                            unsigned char* __restrict__ dstX) {
    int b = blockIdx.x;
    if (b < W_BLOCKS) {
        int t = b * 256 + threadIdx.x;           // 0 .. N*K/8-1
        int n = t >> 9;                          // K/8 = 512 chunks per row
        int ck = t & 511;
        int kstep = ck >> 3, s = ck & 7;
        int nt = n >> 7, r = n & 127;

        const int4 p4 = *reinterpret_cast<const int4*>(wp + (size_t)n * (K_DIM / 2) + kstep * 32 + s * 4);
        float scale = wsc[(size_t)n * (K_DIM / 32) + kstep * 2 + (s >> 2)];

        const int pv[4] = {p4.x, p4.y, p4.z, p4.w};
        unsigned o[8];
        #pragma unroll
        for (int j = 0; j < 4; ++j) {
            unsigned by = (unsigned)pv[j] & 255u;
            o[2 * j]     = f2bf(dec4(by & 15u, scale));
            o[2 * j + 1] = f2bf(dec4((by >> 4) & 15u, scale));
        }
        uint4 v;
        v.x = o[0] | (o[1] << 16);
        v.y = o[2] | (o[3] << 16);
        v.z = o[4] | (o[5] << 16);
        v.w = o[6] | (o[7] << 16);

        size_t off = (size_t)(nt * 64 + kstep) * STRIPE
                   + (size_t)r * 128 + (size_t)((s ^ (r & 7)) << 4);
        *reinterpret_cast<uint4*>(dstW + off) = v;
    } else {
        int t = (b - W_BLOCKS) * 256 + threadIdx.x;   // 0 .. M*K/8-1
        int m = t >> 9;
        int ck = t & 511;
        int kstep = ck >> 3, s = ck & 7;
        int mt = m >> 7, r = m & 127;

        const float4* xp = reinterpret_cast<const float4*>(x + (size_t)m * K_DIM + kstep * 64 + s * 8);
        float4 a = xp[0], c = xp[1];
        uint4 v;
        v.x = f2bf(a.x) | (f2bf(a.y) << 16);
        v.y = f2bf(a.z) | (f2bf(a.w) << 16);
        v.z = f2bf(c.x) | (f2bf(c.y) << 16);
        v.w = f2bf(c.z) | (f2bf(c.w) << 16);

        size_t off = (size_t)(mt * 64 + kstep) * STRIPE
                   + (size_t)r * 128 + (size_t)((s ^ (r & 7)) << 4);
        *reinterpret_cast<uint4*>(dstX + off) = v;
    }
}

// ---------------- Pass 2: 256^2 bf16 GEMM, ring-4, 16x16x32, reg-prefetch (r6) ----------
// BK=32, 512 threads (8 waves, 2M x 4N), per-wave 128x64 = 8x4 frags of 16x16.
// LDS read layout = round-3's (MEASURED zero-conflict): line L = row>>1 (128 B = rows
//   2L,2L+1), slot = (((row&1)<<2)|fg) ^ (L&7), fg = K-quarter (lane>>4).
// Pipeline = round-6's verified 283us: tile t+1's B[0..3]+A[0..3] fragments are
//   register-prefetched during tile t; A[4..7] read under cluster 1; stage tile t+3;
//   vmcnt(4) cadence (one staged tile in flight across each barrier).
// Change vs r6: s_setprio removed (lockstep structure; m190 evidence it costs here).

__global__ __launch_bounds__(512, 2) void gemm_bf16_256(
    const unsigned char* __restrict__ wsA,
    const unsigned char* __restrict__ wsB,
    const float* __restrict__ bias,
    float* __restrict__ out)
{
    __shared__ unsigned char lds[131072];   // [0,64K) = A slots, [64K,128K) = B slots

    // XCD-chunked bijective swizzle
    int id = blockIdx.x;
    int wg = (id & 7) * 64 + (id >> 3);
    int MT = wg & 7;        // 0..7
    int NT = wg >> 3;       // 0..63

    const int tid  = threadIdx.x;
    const int lane = tid & 63;
    const int w    = tid >> 6;
    const int wm   = w >> 2;     // 0..1
    const int wn   = w & 3;      // 0..3
    const int fr   = lane & 15;  // fragment row
    const int fg   = lane >> 4;  // K-quarter 0..3

    const unsigned char* gA = wsA + (size_t)(2 * MT) * TSTRIDE;
    const unsigned char* gB = wsB + (size_t)(2 * NT) * TSTRIDE;

    // ds_read byte addresses (round-3 formulas, zero-conflict verified)
    int addrA[8];
    #pragma unroll
    for (int mi = 0; mi < 8; ++mi) {
        int row = wm * 128 + mi * 16 + fr;
        int L = row >> 1;
        addrA[mi] = L * 128 + (((((row & 1) << 2) | fg) ^ (L & 7)) << 4);
    }
    int addrB[4];
    #pragma unroll
    for (int ni = 0; ni < 4; ++ni) {
        int row = wn * 64 + ni * 16 + fr;
        int L = row >> 1;
        addrB[ni] = L * 128 + (((((row & 1) << 2) | fg) ^ (L & 7)) << 4);
    }

    // staging source offsets (round-3 version, matches the read layout above)
    int offST[2][2];
    #pragma unroll
    for (int j = 0; j < 2; ++j) {
        int c = w * 2 + j;
        int L = c * 8 + (lane >> 3);
        int p = lane & 7;
        int sl = p ^ (L & 7);
        int h = sl >> 2, fgs = sl & 3;
        int row = 2 * L + h;
        #pragma unroll
        for (int kb = 0; kb < 2; ++kb)
            offST[j][kb] = (row >> 7) * TSTRIDE + (row & 127) * 128
                         + ((((kb << 2) | fgs) ^ (row & 7)) << 4);
    }

#define GLDS(SRC, DOFF) __builtin_amdgcn_global_load_lds(                          \
        (const __attribute__((address_space(1))) unsigned int*)(SRC),              \
        (__attribute__((address_space(3))) unsigned int*)(&lds[DOFF]), 16, 0, 0)

#define STAGE_A(KSOFF, KB, SLOT) do {                                              \
        GLDS(gA + (KSOFF) + offST[0][KB], ((SLOT) << 14) + (w * 2 + 0) * 1024);    \
        GLDS(gA + (KSOFF) + offST[1][KB], ((SLOT) << 14) + (w * 2 + 1) * 1024);    \
    } while (0)
#define STAGE_B(KSOFF, KB, SLOT) do {                                              \
        GLDS(gB + (KSOFF) + offST[0][KB], 65536 + ((SLOT) << 14) + (w * 2 + 0) * 1024); \
        GLDS(gB + (KSOFF) + offST[1][KB], 65536 + ((SLOT) << 14) + (w * 2 + 1) * 1024); \
    } while (0)

// prefetch a tile's B[0..3] + A[0..3] fragments into named register arrays
#define READ_PF(PA, PB, SLOT) do {                                                 \
        const unsigned char* La_ = lds + ((SLOT) << 14);                           \
        const unsigned char* Lb_ = lds + 65536 + ((SLOT) << 14);                   \
        _Pragma("unroll") for (int ni = 0; ni < 4; ++ni)                           \
            PB[ni] = *reinterpret_cast<const bf16x8*>(Lb_ + addrB[ni]);            \
        _Pragma("unroll") for (int mi = 0; mi < 4; ++mi)                           \
            PA[mi] = *reinterpret_cast<const bf16x8*>(La_ + addrA[mi]);            \
    } while (0)

    f32x4 acc[8][4];
    #pragma unroll
    for (int mi = 0; mi < 8; ++mi)
        #pragma unroll
        for (int ni = 0; ni < 4; ++ni)
            acc[mi][ni] = (f32x4){0.f, 0.f, 0.f, 0.f};

    bf16x8 pa0[4], pb0[4], pa1[4], pb1[4];   // double-buffered prefetch fragments

    // prologue: stage tiles 0,1,2 into slots 0,1,2; wait tiles 0+1 (vmcnt(4)).
    STAGE_A(0, 0, 0);        STAGE_B(0, 0, 0);
    STAGE_A(0, 1, 1);        STAGE_B(0, 1, 1);
    STAGE_A(STRIPE, 0, 2);   STAGE_B(STRIPE, 0, 2);
    asm volatile("s_waitcnt vmcnt(4)" ::: "memory");
    __builtin_amdgcn_sched_barrier(0);
    __builtin_amdgcn_s_barrier();
    __builtin_amdgcn_sched_barrier(0);
    READ_PF(pa0, pb0, 0);

// one K-tile: cluster1 (mi 0..3) fires from prefetched regs immediately post-barrier;
// A[4..7] read under cluster1, consumed by cluster2; next tile's frags prefetched
// between clusters; stage tile t+3; counted vmcnt (VMN<0 = last tile, no boundary).
#define TILE_BODY(RSLOT, NSLOT, PA, PB, NPA, NPB, DO_STG, STKS, STKB, SSLOT, DO_PF, VMN) do { \
        const unsigned char* la = lds + ((RSLOT) << 14);                           \
        bf16x8 ka[4];                                                              \
        if (DO_STG) STAGE_A(STKS, STKB, SSLOT);                                    \
        _Pragma("unroll") for (int mi = 0; mi < 4; ++mi)                           \
            ka[mi] = *reinterpret_cast<const bf16x8*>(la + addrA[4 + mi]);         \
        _Pragma("unroll") for (int mi = 0; mi < 4; ++mi)                           \
            _Pragma("unroll") for (int ni = 0; ni < 4; ++ni)                       \
                acc[mi][ni] = __builtin_amdgcn_mfma_f32_16x16x32_bf16(             \
                    PA[mi], PB[ni], acc[mi][ni], 0, 0, 0);                         \
        if (DO_STG) STAGE_B(STKS, STKB, SSLOT);                                    \
        if (DO_PF) READ_PF(NPA, NPB, NSLOT);                                       \
        _Pragma("unroll") for (int mi = 0; mi < 4; ++mi)                           \
            _Pragma("unroll") for (int ni = 0; ni < 4; ++ni)                       \
                acc[4 + mi][ni] = __builtin_amdgcn_mfma_f32_16x16x32_bf16(         \
                    ka[mi], PB[ni], acc[4 + mi][ni], 0, 0, 0);                     \
        if ((VMN) >= 0) {                                                          \
            if ((VMN) == 4)      asm volatile("s_waitcnt vmcnt(4)" ::: "memory");  \
            else                 asm volatile("s_waitcnt vmcnt(0)" ::: "memory");  \
            __builtin_amdgcn_sched_barrier(0);                                     \
            __builtin_amdgcn_s_barrier();                                          \
            __builtin_amdgcn_sched_barrier(0);                                     \
        }                                                                          \
    } while (0)

    // main loop: tiles t = 2tp, 2tp+1 for tp = 0..61; stage tile t+3; vmcnt(4) cadence.
    for (int tp = 0; tp < 62; ++tp) {
        const int scur = (tp & 1) << 1;              // slot of tile 2tp (0 or 2)
        const int ks1 = (tp + 1) * STRIPE;           // stage tile 2tp+3 (kb=1)
        const int ks2 = (tp + 2) * STRIPE;           // stage tile 2tp+4 (kb=0)
        TILE_BODY(scur,     scur ^ 1, pa0, pb0, pa1, pb1, 1, ks1, 1, scur ^ 3, 1, 4);
        TILE_BODY(scur ^ 1, scur ^ 2, pa1, pb1, pa0, pb0, 1, ks2, 0, scur,     1, 4);
    }
    // tail: tiles 124..127 in slots 0..3; stage only 127; drain 4 -> 0 -> 0.
    TILE_BODY(0, 1, pa0, pb0, pa1, pb1, 1, 63 * STRIPE, 1, 3, 1, 4);
    TILE_BODY(1, 2, pa1, pb1, pa0, pb0, 0, 0, 0, 0, 1, 0);
    TILE_BODY(2, 3, pa0, pb0, pa1, pb1, 0, 0, 0, 0, 1, 0);
    TILE_BODY(3, 0, pa1, pb1, pa0, pb0, 0, 0, 0, 0, 0, -1);

    // epilogue: bias + tanh-GELU, f32 stores (16x16 C/D layout: col=lane&15,
    // row = (lane>>4)*4 + reg).
    const int bm0 = MT * 256, bn0 = NT * 256;
    #pragma unroll
    for (int mi = 0; mi < 8; ++mi) {
        int row = bm0 + wm * 128 + mi * 16 + fg * 4;
        #pragma unroll
        for (int ni = 0; ni < 4; ++ni) {
            int col = bn0 + wn * 64 + ni * 16 + fr;
            float bv = bias[col];
            float* op = out + (size_t)row * N_DIM + col;
            #pragma unroll
            for (int q = 0; q < 4; ++q) {
                float v = acc[mi][ni][q] + bv;
                op[(size_t)q * N_DIM] = gelu_tanh(v);
            }
        }
    }
#undef TILE_BODY
#undef READ_PF
#undef STAGE_A
#undef STAGE_B
#undef GLDS
}

// ---------------- Fallback: round-1 fused kernel (used only if ws too small) ------------
__global__ __launch_bounds__(256, 2) void nvfp4_gemm(
    const float* __restrict__ x,
    const int*   __restrict__ wp,
    const float* __restrict__ wscale,
    const float* __restrict__ bias,
    float* __restrict__ out)
{
    __shared__ uint4  lsA[128 * 8];
    __shared__ uint4  lsB[128 * 8];
    __shared__ float2 lut[256];

    const int tid = threadIdx.x;
    {
        static const float dectab[16] = {0.f, 0.5f, 1.f, 1.5f, 2.f, 3.f, 4.f, 6.f,
                                         -0.f,-0.5f,-1.f,-1.5f,-2.f,-3.f,-4.f,-6.f};
        lut[tid] = make_float2(dectab[tid & 15], dectab[(tid >> 4) & 15]);
    }

    const int bn0 = blockIdx.x * 128;
    const int bm0 = blockIdx.y * 128;
    const int r = tid >> 1;
    const int h = tid & 1;

    const float4* xp = reinterpret_cast<const float4*>(x + (size_t)(bm0 + r) * K_DIM) + h * 8;
    const uint4*  bp = reinterpret_cast<const uint4*>(wp + (size_t)(bn0 + r) * (K_DIM / 2)) + h * 4;
    const float*  sp = wscale + (size_t)(bn0 + r) * (K_DIM / 32) + h;

    float4 ax[8];
    uint4  bx[4];
    float  scale;
    #pragma unroll
    for (int j = 0; j < 8; ++j) ax[j] = xp[j];
    #pragma unroll
    for (int q = 0; q < 4; ++q) bx[q] = bp[q];
    scale = sp[0];

    f32x4 acc[4][4];
    #pragma unroll
    for (int mi = 0; mi < 4; ++mi)
        #pragma unroll
        for (int ni = 0; ni < 4; ++ni)
            acc[mi][ni] = (f32x4){0.f, 0.f, 0.f, 0.f};

    const int lane = tid & 63;
    const int wid  = tid >> 6;
    const int wm0  = (wid >> 1) * 64;
    const int wn0  = (wid & 1) * 64;
    const int fr   = lane & 15;
    const int fg   = lane >> 4;

    __syncthreads();

    for (int kt = 0; kt < 64; ++kt) {
        #pragma unroll
        for (int j = 0; j < 4; ++j) {
            float4 f0 = ax[2 * j], f1 = ax[2 * j + 1];
            uint4 v;
            v.x = f2bf(f0.x) | (f2bf(f0.y) << 16);
            v.y = f2bf(f0.z) | (f2bf(f0.w) << 16);
            v.z = f2bf(f1.x) | (f2bf(f1.y) << 16);
            v.w = f2bf(f1.z) | (f2bf(f1.w) << 16);
            lsA[(r * 8 + h * 4 + j) ^ (r & 7)] = v;
        }
        #pragma unroll
        for (int q = 0; q < 4; ++q) {
            uint4 p = bx[q];
            float2 d0 = lut[p.x & 255];
            float2 d1 = lut[p.y & 255];
            float2 d2 = lut[p.z & 255];
            float2 d3 = lut[p.w & 255];
            uint4 v;
            v.x = f2bf(d0.x * scale) | (f2bf(d0.y * scale) << 16);
            v.y = f2bf(d1.x * scale) | (f2bf(d1.y * scale) << 16);
            v.z = f2bf(d2.x * scale) | (f2bf(d2.y * scale) << 16);
            v.w = f2bf(d3.x * scale) | (f2bf(d3.y * scale) << 16);
            lsB[(r * 8 + h * 4 + q) ^ (r & 7)] = v;
        }
        __syncthreads();

        if (kt + 1 < 64) {
            #pragma unroll
            for (int j = 0; j < 8; ++j) ax[j] = xp[(kt + 1) * 16 + j];
            #pragma unroll
            for (int q = 0; q < 4; ++q) bx[q] = bp[(kt + 1) * 8 + q];
            scale = sp[(kt + 1) * 2];
        }

        #pragma unroll
        for (int kk = 0; kk < 2; ++kk) {
            bf16x8 af[4], bfr[4];
            #pragma unroll
            for (int mi = 0; mi < 4; ++mi) {
                int row = wm0 + mi * 16 + fr;
                af[mi] = __builtin_bit_cast(bf16x8, lsA[(row * 8 + kk * 4 + fg) ^ (row & 7)]);
            }
            #pragma unroll
            for (int ni = 0; ni < 4; ++ni) {
                int row = wn0 + ni * 16 + fr;
                bfr[ni] = __builtin_bit_cast(bf16x8, lsB[(row * 8 + kk * 4 + fg) ^ (row & 7)]);
            }
            #pragma unroll
            for (int mi = 0; mi < 4; ++mi)
                #pragma unroll
                for (int ni = 0; ni < 4; ++ni)
                    acc[mi][ni] = __builtin_amdgcn_mfma_f32_16x16x32_bf16(
                        af[mi], bfr[ni], acc[mi][ni], 0, 0, 0);
        }
        __syncthreads();
    }

    #pragma unroll
    for (int mi = 0; mi < 4; ++mi) {
        int row = bm0 + wm0 + mi * 16 + fg * 4;
        #pragma unroll
        for (int ni = 0; ni < 4; ++ni) {
            int col = bn0 + wn0 + ni * 16 + fr;
            float bv = bias[col];
            float* op = out + (size_t)row * N_DIM + col;
            #pragma unroll
            for (int q = 0; q < 4; ++q) {
                float v = acc[mi][ni][q] + bv;
                op[(size_t)q * N_DIM] = gelu_tanh(v);
            }
        }
    }
}

extern "C" void kernel_launch(void* const* d_in, const int* in_sizes, int n_in,
                              void* d_out, int out_size, void* d_ws, size_t ws_size,
                              hipStream_t stream) {
    const float* x    = (const float*)d_in[0];
    const int*   wp   = (const int*)d_in[1];
    const float* wsc  = (const float*)d_in[2];
    const float* bias = (const float*)d_in[3];
    float*       out  = (float*)d_out;
    (void)in_sizes; (void)n_in; (void)out_size;

    if (ws_size >= WSB_BYTES + WSA_BYTES) {
        unsigned char* wsB = (unsigned char*)d_ws;
        unsigned char* wsA = wsB + WSB_BYTES;
        prep<<<W_BLOCKS + X_BLOCKS, 256, 0, stream>>>(wp, wsc, x, wsB, wsA);
        gemm_bf16_256<<<(M_DIM / 256) * (N_DIM / 256), 512, 0, stream>>>(wsA, wsB, bias, out);
    } else {
        dim3 grid(N_DIM / 128, M_DIM / 128);
        nvfp4_gemm<<<grid, 256, 0, stream>>>(x, wp, wsc, bias, out);
    }
}

// Round 11
// 321.238 us; speedup vs baseline: 1.6275x; 1.0145x over previous
//
#include <hip/hip_runtime.h>
#include <hip/hip_bf16.h>

typedef short bf16x8 __attribute__((ext_vector_type(8)));
typedef float f32x4 __attribute__((ext_vector_type(4)));

#define K_DIM 4096
#define N_DIM 16384
#define M_DIM 2048
#define STRIPE 16384                       // bytes per (tile128, kstep64) stripe in ws
#define TSTRIDE (64 * STRIPE)              // bytes per 128-row tile (1 MiB)
#define WSB_BYTES ((size_t)N_DIM * K_DIM * 2)   // 134217728
#define WSA_BYTES ((size_t)M_DIM * K_DIM * 2)   // 16777216

__device__ __forceinline__ unsigned f2bf(float f) {
    unsigned u = __builtin_bit_cast(unsigned, f);
    u += 0x7FFFu + ((u >> 16) & 1u);
    return u >> 16;   // RNE, inputs finite
}

// NVFP4 e2m1 nibble -> f32 (branchless), times scale
__device__ __forceinline__ float dec4(unsigned c, float s) {
    unsigned mag = c & 7u;
    unsigned u = (mag >= 2u) ? ((((mag >> 1) + 126u) << 23) | ((mag & 1u) << 22))
                             : (mag == 1u ? 0x3F000000u : 0u);
    u |= (c & 8u) << 28;   // sign
    return __builtin_bit_cast(float, u) * s;
}

__device__ __forceinline__ float gelu_tanh(float v) {
    float c = v + 0.044715f * v * v * v;
    float t = tanhf(0.7978845608028654f * c);
    return 0.5f * v * (1.0f + t);
}

// ---------------- Pass 1a: dequant W -> bf16, tiled + pre-swizzled (r6 verbatim) --------
__global__ __launch_bounds__(256) void dequant_w(const int* __restrict__ wp,
                                                 const float* __restrict__ wsc,
                                                 unsigned char* __restrict__ dst) {
    int t = blockIdx.x * 256 + threadIdx.x;
    int n = t >> 9;
    int ck = t & 511;
    int kstep = ck >> 3, s = ck & 7;
    int nt = n >> 7, r = n & 127;

    const int4 p4 = *reinterpret_cast<const int4*>(wp + (size_t)n * (K_DIM / 2) + kstep * 32 + s * 4);
    float scale = wsc[(size_t)n * (K_DIM / 32) + kstep * 2 + (s >> 2)];

    const int pv[4] = {p4.x, p4.y, p4.z, p4.w};
    unsigned o[8];
    #pragma unroll
    for (int j = 0; j < 4; ++j) {
        unsigned b = (unsigned)pv[j] & 255u;
        o[2 * j]     = f2bf(dec4(b & 15u, scale));
        o[2 * j + 1] = f2bf(dec4((b >> 4) & 15u, scale));
    }
    uint4 v;
    v.x = o[0] | (o[1] << 16);
    v.y = o[2] | (o[3] << 16);
    v.z = o[4] | (o[5] << 16);
    v.w = o[6] | (o[7] << 16);

    size_t off = (size_t)(nt * 64 + kstep) * STRIPE
               + (size_t)r * 128 + (size_t)((s ^ (r & 7)) << 4);
    *reinterpret_cast<uint4*>(dst + off) = v;
}

// ---------------- Pass 1b: x f32 -> bf16, tiled + pre-swizzled (r6 verbatim) ------------
__global__ __launch_bounds__(256) void conv_x(const float* __restrict__ x,
                                              unsigned char* __restrict__ dst) {
    int t = blockIdx.x * 256 + threadIdx.x;
    int m = t >> 9;
    int ck = t & 511;
    int kstep = ck >> 3, s = ck & 7;
    int mt = m >> 7, r = m & 127;

    const float4* xp = reinterpret_cast<const float4*>(x + (size_t)m * K_DIM + kstep * 64 + s * 8);
    float4 a = xp[0], b = xp[1];
    uint4 v;
    v.x = f2bf(a.x) | (f2bf(a.y) << 16);
    v.y = f2bf(a.z) | (f2bf(a.w) << 16);
    v.z = f2bf(b.x) | (f2bf(b.y) << 16);
    v.w = f2bf(b.z) | (f2bf(b.w) << 16);

    size_t off = (size_t)(mt * 64 + kstep) * STRIPE
               + (size_t)r * 128 + (size_t)((s ^ (r & 7)) << 4);
    *reinterpret_cast<uint4*>(dst + off) = v;
}

// ---------------- Pass 2: 256^2 bf16 GEMM -- faithful m201 8-phase schedule -------------
// BK=64, 512 threads (8 waves, 2M x 4N), per-wave 128x64 = 8x4 frags of 16x16.
// LDS 128 KiB: A dbuf d at d*32768, B at 65536+d*32768; within a buf, kk sub-slot at
//   +kk*16384, each sub-slot = r6's verified zero-conflict layout (256 rows x 32 k:
//   line L=row>>1, slot ((row&1)<<2|kq) ^ (L&7)).
// Half-tile (staging unit) = one (op, kk) sub-slot = 16 KiB = 2 global_load_lds/thread
//   -- r6's verified offST/dst machinery verbatim.
// Schedule (m201): 4 phases/K-tile = (kk, mi-half); each phase:
//   { ds_read 4 or 8 x b128 ; stage 1 half-tile ; FENCE ; setprio(1) 16 MFMA setprio(0)
//     ; [vmcnt(6) at phase 4 only] ; FENCE }.
// Staging order (half-tile stream H = 4*T + u, u = {A-kk0,B-kk0,A-kk1,B-kk1}):
//   phase1 of T stages T+1's u3; phases 2,3,4 stage T+2's u0,u1,u2.  vmcnt(6) at the
//   end of T completes exactly through T+1's u3 -> next tile fully resident; 3
//   half-tiles stay in flight (never drains in main loop).

__global__ __launch_bounds__(512, 2) void gemm_bf16_256(
    const unsigned char* __restrict__ wsA,
    const unsigned char* __restrict__ wsB,
    const float* __restrict__ bias,
    float* __restrict__ out)
{
    __shared__ unsigned char lds[131072];

    // XCD-chunked bijective swizzle
    int id = blockIdx.x;
    int wg = (id & 7) * 64 + (id >> 3);
    int MT = wg & 7;        // 0..7
    int NT = wg >> 3;       // 0..63

    const int tid  = threadIdx.x;
    const int lane = tid & 63;
    const int w    = tid >> 6;
    const int wm   = w >> 2;     // 0..1
    const int wn   = w & 3;      // 0..3
    const int fr   = lane & 15;  // fragment row
    const int fg   = lane >> 4;  // K-quarter 0..3 within a kk half

    const unsigned char* gA = wsA + (size_t)(2 * MT) * TSTRIDE;
    const unsigned char* gB = wsB + (size_t)(2 * NT) * TSTRIDE;

    // ds_read byte addresses within a 16 KiB sub-slot (r6 formulas, zero-conflict)
    int addrA[8];
    #pragma unroll
    for (int mi = 0; mi < 8; ++mi) {
        int row = wm * 128 + mi * 16 + fr;
        int L = row >> 1;
        addrA[mi] = L * 128 + (((((row & 1) << 2) | fg) ^ (L & 7)) << 4);
    }
    int addrB[4];
    #pragma unroll
    for (int ni = 0; ni < 4; ++ni) {
        int row = wn * 64 + ni * 16 + fr;
        int L = row >> 1;
        addrB[ni] = L * 128 + (((((row & 1) << 2) | fg) ^ (L & 7)) << 4);
    }

    // staging source offsets (r6 verbatim; kk = which 32-k half of the 64-k stripe)
    int offST[2][2];
    #pragma unroll
    for (int j = 0; j < 2; ++j) {
        int c = w * 2 + j;
        int L = c * 8 + (lane >> 3);
        int p = lane & 7;
        int sl = p ^ (L & 7);
        int h = sl >> 2, kqs = sl & 3;
        int row = 2 * L + h;
        #pragma unroll
        for (int kk = 0; kk < 2; ++kk)
            offST[j][kk] = (row >> 7) * TSTRIDE + (row & 127) * 128
                         + ((((kk << 2) | kqs) ^ (row & 7)) << 4);
    }

#define GLDS(SRC, DOFF) __builtin_amdgcn_global_load_lds(                          \
        (const __attribute__((address_space(1))) unsigned int*)(SRC),              \
        (__attribute__((address_space(3))) unsigned int*)(&lds[DOFF]), 16, 0, 0)

// stage one half-tile: (global base GP, lds op base LB, K-tile KT, kk KK, dbuf D)
#define STG(GP, LB, KT, KK, D) do {                                                \
        GLDS((GP) + (KT) * STRIPE + offST[0][KK],                                  \
             (LB) + (D) * 32768 + (KK) * 16384 + (w * 2 + 0) * 1024);              \
        GLDS((GP) + (KT) * STRIPE + offST[1][KK],                                  \
             (LB) + (D) * 32768 + (KK) * 16384 + (w * 2 + 1) * 1024);              \
    } while (0)

#define FENCE() do {                                                               \
        __builtin_amdgcn_sched_barrier(0);                                         \
        __builtin_amdgcn_s_barrier();                                              \
        __builtin_amdgcn_sched_barrier(0);                                         \
    } while (0)

    f32x4 acc[8][4];
    #pragma unroll
    for (int mi = 0; mi < 8; ++mi)
        #pragma unroll
        for (int ni = 0; ni < 4; ++ni)
            acc[mi][ni] = (f32x4){0.f, 0.f, 0.f, 0.f};

    bf16x8 aa[4], bb[4];

// one phase: read B (if RDB) + A[MB..MB+3] of (buf C, half KK); optional stage;
// FENCE; 16 MFMA; optional vmcnt; trailing FENCE (unless last phase of kernel).
#define PHASE(C, KK, MB, RDB, DOSTG, SGP, SLB, SKT, SKK, SD, VMN, ENDB) do {       \
        const unsigned char* la_ = lds + (C) * 32768 + (KK) * 16384;               \
        const unsigned char* lb_ = lds + 65536 + (C) * 32768 + (KK) * 16384;       \
        if (RDB) {                                                                 \
            _Pragma("unroll") for (int ni = 0; ni < 4; ++ni)                       \
                bb[ni] = *reinterpret_cast<const bf16x8*>(lb_ + addrB[ni]);        \
        }                                                                          \
        _Pragma("unroll") for (int mi = 0; mi < 4; ++mi)                           \
            aa[mi] = *reinterpret_cast<const bf16x8*>(la_ + addrA[(MB) + mi]);     \
        if (DOSTG) STG(SGP, SLB, SKT, SKK, SD);                                    \
        FENCE();                                                                   \
        __builtin_amdgcn_s_setprio(1);                                             \
        _Pragma("unroll") for (int mi = 0; mi < 4; ++mi)                           \
            _Pragma("unroll") for (int ni = 0; ni < 4; ++ni)                       \
                acc[(MB) + mi][ni] = __builtin_amdgcn_mfma_f32_16x16x32_bf16(      \
                    aa[mi], bb[ni], acc[(MB) + mi][ni], 0, 0, 0);                  \
        __builtin_amdgcn_s_setprio(0);                                             \
        if ((VMN) == 6) { asm volatile("s_waitcnt vmcnt(6)" ::: "memory");         \
                          __builtin_amdgcn_sched_barrier(0); }                     \
        else if ((VMN) == 0) { asm volatile("s_waitcnt vmcnt(0)" ::: "memory");    \
                               __builtin_amdgcn_sched_barrier(0); }                \
        if (ENDB) FENCE();                                                         \
    } while (0)

// full K-tile T in buf C, staging T+1's u3 then T+2's u0,u1,u2; vmcnt(6) at phase 4.
#define KTILE_FULL(C, KT1, KT2) do {                                               \
        PHASE(C, 0, 0, 1, 1, gB, 65536, KT1, 1, (C) ^ 1, -1, 1);                   \
        PHASE(C, 0, 4, 0, 1, gA, 0,     KT2, 0, (C),     -1, 1);                   \
        PHASE(C, 1, 0, 1, 1, gB, 65536, KT2, 0, (C),     -1, 1);                   \
        PHASE(C, 1, 4, 0, 1, gA, 0,     KT2, 1, (C),      6, 1);                   \
    } while (0)

    // prologue: half-tiles H0..H6 = tile0{A0,B0,A1,B1} + tile1{A0,B0,A1}; vmcnt(6)
    // completes tile 0 (8 loads), leaves tile 1's u0..u2 in flight.
    STG(gA, 0,     0, 0, 0);
    STG(gB, 65536, 0, 0, 0);
    STG(gA, 0,     0, 1, 0);
    STG(gB, 65536, 0, 1, 0);
    STG(gA, 0,     1, 0, 1);
    STG(gB, 65536, 1, 0, 1);
    STG(gA, 0,     1, 1, 1);
    asm volatile("s_waitcnt vmcnt(6)" ::: "memory");
    FENCE();

    // main loop: tiles T = 0..61 (pairs), full staging, counted vmcnt(6).
    for (int tp = 0; tp < 31; ++tp) {
        KTILE_FULL(0, 2 * tp + 1, 2 * tp + 2);
        KTILE_FULL(1, 2 * tp + 2, 2 * tp + 3);
    }
    // T=62 (buf 0): stage only tile 63's u3 (phase 1); drain at phase 4.
    PHASE(0, 0, 0, 1, 1, gB, 65536, 63, 1, 1, -1, 1);
    PHASE(0, 0, 4, 0, 0, gA, 0, 0, 0, 0, -1, 1);
    PHASE(0, 1, 0, 1, 0, gA, 0, 0, 0, 0, -1, 1);
    PHASE(0, 1, 4, 0, 0, gA, 0, 0, 0, 0,  0, 1);
    // T=63 (buf 1): compute only.
    PHASE(1, 0, 0, 1, 0, gA, 0, 0, 0, 0, -1, 1);
    PHASE(1, 0, 4, 0, 0, gA, 0, 0, 0, 0, -1, 1);
    PHASE(1, 1, 0, 1, 0, gA, 0, 0, 0, 0, -1, 1);
    PHASE(1, 1, 4, 0, 0, gA, 0, 0, 0, 0, -1, 0);

    // epilogue: bias + tanh-GELU, f32 stores (16x16 C/D: col=lane&15, row=(lane>>4)*4+q)
    const int bm0 = MT * 256, bn0 = NT * 256;
    #pragma unroll
    for (int mi = 0; mi < 8; ++mi) {
        int row = bm0 + wm * 128 + mi * 16 + fg * 4;
        #pragma unroll
        for (int ni = 0; ni < 4; ++ni) {
            int col = bn0 + wn * 64 + ni * 16 + fr;
            float bv = bias[col];
            float* op = out + (size_t)row * N_DIM + col;
            #pragma unroll
            for (int q = 0; q < 4; ++q) {
                float v = acc[mi][ni][q] + bv;
                op[(size_t)q * N_DIM] = gelu_tanh(v);
            }
        }
    }
#undef KTILE_FULL
#undef PHASE
#undef FENCE
#undef STG
#undef GLDS
}

// ---------------- Fallback: round-1 fused kernel (used only if ws too small) ------------
__global__ __launch_bounds__(256, 2) void nvfp4_gemm(
    const float* __restrict__ x,
    const int*   __restrict__ wp,
    const float* __restrict__ wscale,
    const float* __restrict__ bias,
    float* __restrict__ out)
{
    __shared__ uint4  lsA[128 * 8];
    __shared__ uint4  lsB[128 * 8];
    __shared__ float2 lut[256];

    const int tid = threadIdx.x;
    {
        static const float dectab[16] = {0.f, 0.5f, 1.f, 1.5f, 2.f, 3.f, 4.f, 6.f,
                                         -0.f,-0.5f,-1.f,-1.5f,-2.f,-3.f,-4.f,-6.f};
        lut[tid] = make_float2(dectab[tid & 15], dectab[(tid >> 4) & 15]);
    }

    const int bn0 = blockIdx.x * 128;
    const int bm0 = blockIdx.y * 128;
    const int r = tid >> 1;
    const int h = tid & 1;

    const float4* xp = reinterpret_cast<const float4*>(x + (size_t)(bm0 + r) * K_DIM) + h * 8;
    const uint4*  bp = reinterpret_cast<const uint4*>(wp + (size_t)(bn0 + r) * (K_DIM / 2)) + h * 4;
    const float*  sp = wscale + (size_t)(bn0 + r) * (K_DIM / 32) + h;

    float4 ax[8];
    uint4  bx[4];
    float  scale;
    #pragma unroll
    for (int j = 0; j < 8; ++j) ax[j] = xp[j];
    #pragma unroll
    for (int q = 0; q < 4; ++q) bx[q] = bp[q];
    scale = sp[0];

    f32x4 acc[4][4];
    #pragma unroll
    for (int mi = 0; mi < 4; ++mi)
        #pragma unroll
        for (int ni = 0; ni < 4; ++ni)
            acc[mi][ni] = (f32x4){0.f, 0.f, 0.f, 0.f};

    const int lane = tid & 63;
    const int wid  = tid >> 6;
    const int wm0  = (wid >> 1) * 64;
    const int wn0  = (wid & 1) * 64;
    const int fr   = lane & 15;
    const int fg   = lane >> 4;

    __syncthreads();

    for (int kt = 0; kt < 64; ++kt) {
        #pragma unroll
        for (int j = 0; j < 4; ++j) {
            float4 f0 = ax[2 * j], f1 = ax[2 * j + 1];
            uint4 v;
            v.x = f2bf(f0.x) | (f2bf(f0.y) << 16);
            v.y = f2bf(f0.z) | (f2bf(f0.w) << 16);
            v.z = f2bf(f1.x) | (f2bf(f1.y) << 16);
            v.w = f2bf(f1.z) | (f2bf(f1.w) << 16);
            lsA[(r * 8 + h * 4 + j) ^ (r & 7)] = v;
        }
        #pragma unroll
        for (int q = 0; q < 4; ++q) {
            uint4 p = bx[q];
            float2 d0 = lut[p.x & 255];
            float2 d1 = lut[p.y & 255];
            float2 d2 = lut[p.z & 255];
            float2 d3 = lut[p.w & 255];
            uint4 v;
            v.x = f2bf(d0.x * scale) | (f2bf(d0.y * scale) << 16);
            v.y = f2bf(d1.x * scale) | (f2bf(d1.y * scale) << 16);
            v.z = f2bf(d2.x * scale) | (f2bf(d2.y * scale) << 16);
            v.w = f2bf(d3.x * scale) | (f2bf(d3.y * scale) << 16);
            lsB[(r * 8 + h * 4 + q) ^ (r & 7)] = v;
        }
        __syncthreads();

        if (kt + 1 < 64) {
            #pragma unroll
            for (int j = 0; j < 8; ++j) ax[j] = xp[(kt + 1) * 16 + j];
            #pragma unroll
            for (int q = 0; q < 4; ++q) bx[q] = bp[(kt + 1) * 8 + q];
            scale = sp[(kt + 1) * 2];
        }

        #pragma unroll
        for (int kk = 0; kk < 2; ++kk) {
            bf16x8 af[4], bfr[4];
            #pragma unroll
            for (int mi = 0; mi < 4; ++mi) {
                int row = wm0 + mi * 16 + fr;
                af[mi] = __builtin_bit_cast(bf16x8, lsA[(row * 8 + kk * 4 + fg) ^ (row & 7)]);
            }
            #pragma unroll
            for (int ni = 0; ni < 4; ++ni) {
                int row = wn0 + ni * 16 + fr;
                bfr[ni] = __builtin_bit_cast(bf16x8, lsB[(row * 8 + kk * 4 + fg) ^ (row & 7)]);
            }
            #pragma unroll
            for (int mi = 0; mi < 4; ++mi)
                #pragma unroll
                for (int ni = 0; ni < 4; ++ni)
                    acc[mi][ni] = __builtin_amdgcn_mfma_f32_16x16x32_bf16(
                        af[mi], bfr[ni], acc[mi][ni], 0, 0, 0);
        }
        __syncthreads();
    }

    #pragma unroll
    for (int mi = 0; mi < 4; ++mi) {
        int row = bm0 + wm0 + mi * 16 + fg * 4;
        #pragma unroll
        for (int ni = 0; ni < 4; ++ni) {
            int col = bn0 + wn0 + ni * 16 + fr;
            float bv = bias[col];
            float* op = out + (size_t)row * N_DIM + col;
            #pragma unroll
            for (int q = 0; q < 4; ++q) {
                float v = acc[mi][ni][q] + bv;
                op[(size_t)q * N_DIM] = gelu_tanh(v);
            }
        }
    }
}

extern "C" void kernel_launch(void* const* d_in, const int* in_sizes, int n_in,
                              void* d_out, int out_size, void* d_ws, size_t ws_size,
                              hipStream_t stream) {
    const float* x    = (const float*)d_in[0];
    const int*   wp   = (const int*)d_in[1];
    const float* wsc  = (const float*)d_in[2];
    const float* bias = (const float*)d_in[3];
    float*       out  = (float*)d_out;
    (void)in_sizes; (void)n_in; (void)out_size;

    if (ws_size >= WSB_BYTES + WSA_BYTES) {
        unsigned char* wsB = (unsigned char*)d_ws;
        unsigned char* wsA = wsB + WSB_BYTES;
        dequant_w<<<(N_DIM * (K_DIM / 8)) / 256, 256, 0, stream>>>(wp, wsc, wsB);
        conv_x<<<(M_DIM * (K_DIM / 8)) / 256, 256, 0, stream>>>(x, wsA);
        gemm_bf16_256<<<(M_DIM / 256) * (N_DIM / 256), 512, 0, stream>>>(wsA, wsB, bias, out);
    } else {
        dim3 grid(N_DIM / 128, M_DIM / 128);
        nvfp4_gemm<<<grid, 256, 0, stream>>>(x, wp, wsc, bias, out);
    }
}

// Round 12
// 304.485 us; speedup vs baseline: 1.7170x; 1.0550x over previous
//
#include <hip/hip_runtime.h>
#include <hip/hip_bf16.h>

typedef short bf16x8 __attribute__((ext_vector_type(8)));
typedef float f32x4 __attribute__((ext_vector_type(4)));

#define K_DIM 4096
#define N_DIM 16384
#define M_DIM 2048
#define STRIPE 16384                       // bytes per (tile128, kstep64) stripe in ws
#define TSTRIDE (64 * STRIPE)              // bytes per 128-row tile (1 MiB)
#define WSB_BYTES ((size_t)N_DIM * K_DIM * 2)   // 134217728
#define WSA_BYTES ((size_t)M_DIM * K_DIM * 2)   // 16777216

__device__ __forceinline__ unsigned f2bf(float f) {
    unsigned u = __builtin_bit_cast(unsigned, f);
    u += 0x7FFFu + ((u >> 16) & 1u);
    return u >> 16;   // RNE, inputs finite
}

// NVFP4 e2m1 nibble -> f32 (branchless), times scale
__device__ __forceinline__ float dec4(unsigned c, float s) {
    unsigned mag = c & 7u;
    unsigned u = (mag >= 2u) ? ((((mag >> 1) + 126u) << 23) | ((mag & 1u) << 22))
                             : (mag == 1u ? 0x3F000000u : 0u);
    u |= (c & 8u) << 28;   // sign
    return __builtin_bit_cast(float, u) * s;
}

// fast tanh-GELU: tanh(z) = (1-t)*rcp(1+t), t = 2^(-2*log2(e)*z), z = 0.79788*c.
// clamp exponent at 80 so t never overflows (th -> -1 exactly in fp); v_exp_f32 and
// v_rcp_f32 are ~1 ulp -> abs error ~1e-4 on |out|<=20, negligible vs 0.125 absmax.
__device__ __forceinline__ float fexp2(float x) {
    float r; asm("v_exp_f32 %0, %1" : "=v"(r) : "v"(x)); return r;
}
__device__ __forceinline__ float gelu_tanh(float v) {
    float c = v + 0.044715f * v * v * v;
    float x = fminf(-2.3022084f * c, 80.0f);   // -2*log2(e)*0.7978845608 * c
    float t = fexp2(x);
    float th = (1.0f - t) * __builtin_amdgcn_rcpf(1.0f + t);
    return 0.5f * v * (1.0f + th);
}

// ---------------- Pass 1a: dequant W -> bf16, tiled + pre-swizzled (r6 verbatim) --------
__global__ __launch_bounds__(256) void dequant_w(const int* __restrict__ wp,
                                                 const float* __restrict__ wsc,
                                                 unsigned char* __restrict__ dst) {
    int t = blockIdx.x * 256 + threadIdx.x;
    int n = t >> 9;
    int ck = t & 511;
    int kstep = ck >> 3, s = ck & 7;
    int nt = n >> 7, r = n & 127;

    const int4 p4 = *reinterpret_cast<const int4*>(wp + (size_t)n * (K_DIM / 2) + kstep * 32 + s * 4);
    float scale = wsc[(size_t)n * (K_DIM / 32) + kstep * 2 + (s >> 2)];

    const int pv[4] = {p4.x, p4.y, p4.z, p4.w};
    unsigned o[8];
    #pragma unroll
    for (int j = 0; j < 4; ++j) {
        unsigned b = (unsigned)pv[j] & 255u;
        o[2 * j]     = f2bf(dec4(b & 15u, scale));
        o[2 * j + 1] = f2bf(dec4((b >> 4) & 15u, scale));
    }
    uint4 v;
    v.x = o[0] | (o[1] << 16);
    v.y = o[2] | (o[3] << 16);
    v.z = o[4] | (o[5] << 16);
    v.w = o[6] | (o[7] << 16);

    size_t off = (size_t)(nt * 64 + kstep) * STRIPE
               + (size_t)r * 128 + (size_t)((s ^ (r & 7)) << 4);
    *reinterpret_cast<uint4*>(dst + off) = v;
}

// ---------------- Pass 1b: x f32 -> bf16, tiled + pre-swizzled (r6 verbatim) ------------
__global__ __launch_bounds__(256) void conv_x(const float* __restrict__ x,
                                              unsigned char* __restrict__ dst) {
    int t = blockIdx.x * 256 + threadIdx.x;
    int m = t >> 9;
    int ck = t & 511;
    int kstep = ck >> 3, s = ck & 7;
    int mt = m >> 7, r = m & 127;

    const float4* xp = reinterpret_cast<const float4*>(x + (size_t)m * K_DIM + kstep * 64 + s * 8);
    float4 a = xp[0], b = xp[1];
    uint4 v;
    v.x = f2bf(a.x) | (f2bf(a.y) << 16);
    v.y = f2bf(a.z) | (f2bf(a.w) << 16);
    v.z = f2bf(b.x) | (f2bf(b.y) << 16);
    v.w = f2bf(b.z) | (f2bf(b.w) << 16);

    size_t off = (size_t)(mt * 64 + kstep) * STRIPE
               + (size_t)r * 128 + (size_t)((s ^ (r & 7)) << 4);
    *reinterpret_cast<uint4*>(dst + off) = v;
}

// ---------------- Pass 2: 256^2 bf16 GEMM, ring-4, 16x16x32, reg-prefetch (r10) ---------
// BK=32, 512 threads (8 waves, 2M x 4N), per-wave 128x64 = 8x4 frags of 16x16.
// Best-measured structure (r6/r10, 279-285us, MfmaUtil ~45%, conflicts 0):
//   ring-4 LDS slots, stage(t+3) during tile t, counted vmcnt(4) per tile,
//   zero-conflict r3 read layout, cross-tile reg-prefetch of tile t+1's A[0..3]+B[0..3];
//   no setprio (lockstep structure, m190-consistent neutral).
// Only change vs r10: fast exp2-based tanh-GELU epilogue.

__global__ __launch_bounds__(512, 2) void gemm_bf16_256(
    const unsigned char* __restrict__ wsA,
    const unsigned char* __restrict__ wsB,
    const float* __restrict__ bias,
    float* __restrict__ out)
{
    __shared__ unsigned char lds[131072];   // [0,64K) = A slots, [64K,128K) = B slots

    // XCD-chunked bijective swizzle
    int id = blockIdx.x;
    int wg = (id & 7) * 64 + (id >> 3);
    int MT = wg & 7;        // 0..7
    int NT = wg >> 3;       // 0..63

    const int tid  = threadIdx.x;
    const int lane = tid & 63;
    const int w    = tid >> 6;
    const int wm   = w >> 2;     // 0..1
    const int wn   = w & 3;      // 0..3
    const int fr   = lane & 15;  // fragment row
    const int fg   = lane >> 4;  // K-quarter 0..3

    const unsigned char* gA = wsA + (size_t)(2 * MT) * TSTRIDE;
    const unsigned char* gB = wsB + (size_t)(2 * NT) * TSTRIDE;

    // ds_read byte addresses (round-3 formulas, zero-conflict verified)
    int addrA[8];
    #pragma unroll
    for (int mi = 0; mi < 8; ++mi) {
        int row = wm * 128 + mi * 16 + fr;
        int L = row >> 1;
        addrA[mi] = L * 128 + (((((row & 1) << 2) | fg) ^ (L & 7)) << 4);
    }
    int addrB[4];
    #pragma unroll
    for (int ni = 0; ni < 4; ++ni) {
        int row = wn * 64 + ni * 16 + fr;
        int L = row >> 1;
        addrB[ni] = L * 128 + (((((row & 1) << 2) | fg) ^ (L & 7)) << 4);
    }

    // staging source offsets (round-3 version, matches the read layout above)
    int offST[2][2];
    #pragma unroll
    for (int j = 0; j < 2; ++j) {
        int c = w * 2 + j;
        int L = c * 8 + (lane >> 3);
        int p = lane & 7;
        int sl = p ^ (L & 7);
        int h = sl >> 2, fgs = sl & 3;
        int row = 2 * L + h;
        #pragma unroll
        for (int kb = 0; kb < 2; ++kb)
            offST[j][kb] = (row >> 7) * TSTRIDE + (row & 127) * 128
                         + ((((kb << 2) | fgs) ^ (row & 7)) << 4);
    }

#define GLDS(SRC, DOFF) __builtin_amdgcn_global_load_lds(                          \
        (const __attribute__((address_space(1))) unsigned int*)(SRC),              \
        (__attribute__((address_space(3))) unsigned int*)(&lds[DOFF]), 16, 0, 0)

#define STAGE_A(KSOFF, KB, SLOT) do {                                              \
        GLDS(gA + (KSOFF) + offST[0][KB], ((SLOT) << 14) + (w * 2 + 0) * 1024);    \
        GLDS(gA + (KSOFF) + offST[1][KB], ((SLOT) << 14) + (w * 2 + 1) * 1024);    \
    } while (0)
#define STAGE_B(KSOFF, KB, SLOT) do {                                              \
        GLDS(gB + (KSOFF) + offST[0][KB], 65536 + ((SLOT) << 14) + (w * 2 + 0) * 1024); \
        GLDS(gB + (KSOFF) + offST[1][KB], 65536 + ((SLOT) << 14) + (w * 2 + 1) * 1024); \
    } while (0)

// prefetch a tile's B[0..3] + A[0..3] fragments into named register arrays
#define READ_PF(PA, PB, SLOT) do {                                                 \
        const unsigned char* La_ = lds + ((SLOT) << 14);                           \
        const unsigned char* Lb_ = lds + 65536 + ((SLOT) << 14);                   \
        _Pragma("unroll") for (int ni = 0; ni < 4; ++ni)                           \
            PB[ni] = *reinterpret_cast<const bf16x8*>(Lb_ + addrB[ni]);            \
        _Pragma("unroll") for (int mi = 0; mi < 4; ++mi)                           \
            PA[mi] = *reinterpret_cast<const bf16x8*>(La_ + addrA[mi]);            \
    } while (0)

    f32x4 acc[8][4];
    #pragma unroll
    for (int mi = 0; mi < 8; ++mi)
        #pragma unroll
        for (int ni = 0; ni < 4; ++ni)
            acc[mi][ni] = (f32x4){0.f, 0.f, 0.f, 0.f};

    bf16x8 pa0[4], pb0[4], pa1[4], pb1[4];   // double-buffered prefetch fragments

    // prologue: stage tiles 0,1,2 into slots 0,1,2; wait tiles 0+1 (vmcnt(4)).
    STAGE_A(0, 0, 0);        STAGE_B(0, 0, 0);
    STAGE_A(0, 1, 1);        STAGE_B(0, 1, 1);
    STAGE_A(STRIPE, 0, 2);   STAGE_B(STRIPE, 0, 2);
    asm volatile("s_waitcnt vmcnt(4)" ::: "memory");
    __builtin_amdgcn_sched_barrier(0);
    __builtin_amdgcn_s_barrier();
    __builtin_amdgcn_sched_barrier(0);
    READ_PF(pa0, pb0, 0);

// one K-tile: cluster1 (mi 0..3) fires from prefetched regs immediately post-barrier;
// A[4..7] read under cluster1, consumed by cluster2; next tile's frags prefetched
// between clusters; stage tile t+3; counted vmcnt (VMN<0 = last tile, no boundary).
#define TILE_BODY(RSLOT, NSLOT, PA, PB, NPA, NPB, DO_STG, STKS, STKB, SSLOT, DO_PF, VMN) do { \
        const unsigned char* la = lds + ((RSLOT) << 14);                           \
        bf16x8 ka[4];                                                              \
        if (DO_STG) STAGE_A(STKS, STKB, SSLOT);                                    \
        _Pragma("unroll") for (int mi = 0; mi < 4; ++mi)                           \
            ka[mi] = *reinterpret_cast<const bf16x8*>(la + addrA[4 + mi]);         \
        _Pragma("unroll") for (int mi = 0; mi < 4; ++mi)                           \
            _Pragma("unroll") for (int ni = 0; ni < 4; ++ni)                       \
                acc[mi][ni] = __builtin_amdgcn_mfma_f32_16x16x32_bf16(             \
                    PA[mi], PB[ni], acc[mi][ni], 0, 0, 0);                         \
        if (DO_STG) STAGE_B(STKS, STKB, SSLOT);                                    \
        if (DO_PF) READ_PF(NPA, NPB, NSLOT);                                       \
        _Pragma("unroll") for (int mi = 0; mi < 4; ++mi)                           \
            _Pragma("unroll") for (int ni = 0; ni < 4; ++ni)                       \
                acc[4 + mi][ni] = __builtin_amdgcn_mfma_f32_16x16x32_bf16(         \
                    ka[mi], PB[ni], acc[4 + mi][ni], 0, 0, 0);                     \
        if ((VMN) >= 0) {                                                          \
            if ((VMN) == 4)      asm volatile("s_waitcnt vmcnt(4)" ::: "memory");  \
            else                 asm volatile("s_waitcnt vmcnt(0)" ::: "memory");  \
            __builtin_amdgcn_sched_barrier(0);                                     \
            __builtin_amdgcn_s_barrier();                                          \
            __builtin_amdgcn_sched_barrier(0);                                     \
        }                                                                          \
    } while (0)

    // main loop: tiles t = 2tp, 2tp+1 for tp = 0..61; stage tile t+3; vmcnt(4) cadence.
    for (int tp = 0; tp < 62; ++tp) {
        const int scur = (tp & 1) << 1;              // slot of tile 2tp (0 or 2)
        const int ks1 = (tp + 1) * STRIPE;           // stage tile 2tp+3 (kb=1)
        const int ks2 = (tp + 2) * STRIPE;           // stage tile 2tp+4 (kb=0)
        TILE_BODY(scur,     scur ^ 1, pa0, pb0, pa1, pb1, 1, ks1, 1, scur ^ 3, 1, 4);
        TILE_BODY(scur ^ 1, scur ^ 2, pa1, pb1, pa0, pb0, 1, ks2, 0, scur,     1, 4);
    }
    // tail: tiles 124..127 in slots 0..3; stage only 127; drain 4 -> 0 -> 0.
    TILE_BODY(0, 1, pa0, pb0, pa1, pb1, 1, 63 * STRIPE, 1, 3, 1, 4);
    TILE_BODY(1, 2, pa1, pb1, pa0, pb0, 0, 0, 0, 0, 1, 0);
    TILE_BODY(2, 3, pa0, pb0, pa1, pb1, 0, 0, 0, 0, 1, 0);
    TILE_BODY(3, 0, pa1, pb1, pa0, pb0, 0, 0, 0, 0, 0, -1);

    // epilogue: bias + fast tanh-GELU, f32 stores (16x16 C/D layout: col=lane&15,
    // row = (lane>>4)*4 + reg).
    const int bm0 = MT * 256, bn0 = NT * 256;
    #pragma unroll
    for (int mi = 0; mi < 8; ++mi) {
        int row = bm0 + wm * 128 + mi * 16 + fg * 4;
        #pragma unroll
        for (int ni = 0; ni < 4; ++ni) {
            int col = bn0 + wn * 64 + ni * 16 + fr;
            float bv = bias[col];
            float* op = out + (size_t)row * N_DIM + col;
            #pragma unroll
            for (int q = 0; q < 4; ++q) {
                float v = acc[mi][ni][q] + bv;
                op[(size_t)q * N_DIM] = gelu_tanh(v);
            }
        }
    }
#undef TILE_BODY
#undef READ_PF
#undef STAGE_A
#undef STAGE_B
#undef GLDS
}

// ---------------- Fallback: round-1 fused kernel (used only if ws too small) ------------
__global__ __launch_bounds__(256, 2) void nvfp4_gemm(
    const float* __restrict__ x,
    const int*   __restrict__ wp,
    const float* __restrict__ wscale,
    const float* __restrict__ bias,
    float* __restrict__ out)
{
    __shared__ uint4  lsA[128 * 8];
    __shared__ uint4  lsB[128 * 8];
    __shared__ float2 lut[256];

    const int tid = threadIdx.x;
    {
        static const float dectab[16] = {0.f, 0.5f, 1.f, 1.5f, 2.f, 3.f, 4.f, 6.f,
                                         -0.f,-0.5f,-1.f,-1.5f,-2.f,-3.f,-4.f,-6.f};
        lut[tid] = make_float2(dectab[tid & 15], dectab[(tid >> 4) & 15]);
    }

    const int bn0 = blockIdx.x * 128;
    const int bm0 = blockIdx.y * 128;
    const int r = tid >> 1;
    const int h = tid & 1;

    const float4* xp = reinterpret_cast<const float4*>(x + (size_t)(bm0 + r) * K_DIM) + h * 8;
    const uint4*  bp = reinterpret_cast<const uint4*>(wp + (size_t)(bn0 + r) * (K_DIM / 2)) + h * 4;
    const float*  sp = wscale + (size_t)(bn0 + r) * (K_DIM / 32) + h;

    float4 ax[8];
    uint4  bx[4];
    float  scale;
    #pragma unroll
    for (int j = 0; j < 8; ++j) ax[j] = xp[j];
    #pragma unroll
    for (int q = 0; q < 4; ++q) bx[q] = bp[q];
    scale = sp[0];

    f32x4 acc[4][4];
    #pragma unroll
    for (int mi = 0; mi < 4; ++mi)
        #pragma unroll
        for (int ni = 0; ni < 4; ++ni)
            acc[mi][ni] = (f32x4){0.f, 0.f, 0.f, 0.f};

    const int lane = tid & 63;
    const int wid  = tid >> 6;
    const int wm0  = (wid >> 1) * 64;
    const int wn0  = (wid & 1) * 64;
    const int fr   = lane & 15;
    const int fg   = lane >> 4;

    __syncthreads();

    for (int kt = 0; kt < 64; ++kt) {
        #pragma unroll
        for (int j = 0; j < 4; ++j) {
            float4 f0 = ax[2 * j], f1 = ax[2 * j + 1];
            uint4 v;
            v.x = f2bf(f0.x) | (f2bf(f0.y) << 16);
            v.y = f2bf(f0.z) | (f2bf(f0.w) << 16);
            v.z = f2bf(f1.x) | (f2bf(f1.y) << 16);
            v.w = f2bf(f1.z) | (f2bf(f1.w) << 16);
            lsA[(r * 8 + h * 4 + j) ^ (r & 7)] = v;
        }
        #pragma unroll
        for (int q = 0; q < 4; ++q) {
            uint4 p = bx[q];
            float2 d0 = lut[p.x & 255];
            float2 d1 = lut[p.y & 255];
            float2 d2 = lut[p.z & 255];
            float2 d3 = lut[p.w & 255];
            uint4 v;
            v.x = f2bf(d0.x * scale) | (f2bf(d0.y * scale) << 16);
            v.y = f2bf(d1.x * scale) | (f2bf(d1.y * scale) << 16);
            v.z = f2bf(d2.x * scale) | (f2bf(d2.y * scale) << 16);
            v.w = f2bf(d3.x * scale) | (f2bf(d3.y * scale) << 16);
            lsB[(r * 8 + h * 4 + q) ^ (r & 7)] = v;
        }
        __syncthreads();

        if (kt + 1 < 64) {
            #pragma unroll
            for (int j = 0; j < 8; ++j) ax[j] = xp[(kt + 1) * 16 + j];
            #pragma unroll
            for (int q = 0; q < 4; ++q) bx[q] = bp[(kt + 1) * 8 + q];
            scale = sp[(kt + 1) * 2];
        }

        #pragma unroll
        for (int kk = 0; kk < 2; ++kk) {
            bf16x8 af[4], bfr[4];
            #pragma unroll
            for (int mi = 0; mi < 4; ++mi) {
                int row = wm0 + mi * 16 + fr;
                af[mi] = __builtin_bit_cast(bf16x8, lsA[(row * 8 + kk * 4 + fg) ^ (row & 7)]);
            }
            #pragma unroll
            for (int ni = 0; ni < 4; ++ni) {
                int row = wn0 + ni * 16 + fr;
                bfr[ni] = __builtin_bit_cast(bf16x8, lsB[(row * 8 + kk * 4 + fg) ^ (row & 7)]);
            }
            #pragma unroll
            for (int mi = 0; mi < 4; ++mi)
                #pragma unroll
                for (int ni = 0; ni < 4; ++ni)
                    acc[mi][ni] = __builtin_amdgcn_mfma_f32_16x16x32_bf16(
                        af[mi], bfr[ni], acc[mi][ni], 0, 0, 0);
        }
        __syncthreads();
    }

    #pragma unroll
    for (int mi = 0; mi < 4; ++mi) {
        int row = bm0 + wm0 + mi * 16 + fg * 4;
        #pragma unroll
        for (int ni = 0; ni < 4; ++ni) {
            int col = bn0 + wn0 + ni * 16 + fr;
            float bv = bias[col];
            float* op = out + (size_t)row * N_DIM + col;
            #pragma unroll
            for (int q = 0; q < 4; ++q) {
                float v = acc[mi][ni][q] + bv;
                op[(size_t)q * N_DIM] = gelu_tanh(v);
            }
        }
    }
}

extern "C" void kernel_launch(void* const* d_in, const int* in_sizes, int n_in,
                              void* d_out, int out_size, void* d_ws, size_t ws_size,
                              hipStream_t stream) {
    const float* x    = (const float*)d_in[0];
    const int*   wp   = (const int*)d_in[1];
    const float* wsc  = (const float*)d_in[2];
    const float* bias = (const float*)d_in[3];
    float*       out  = (float*)d_out;
    (void)in_sizes; (void)n_in; (void)out_size;

    if (ws_size >= WSB_BYTES + WSA_BYTES) {
        unsigned char* wsB = (unsigned char*)d_ws;
        unsigned char* wsA = wsB + WSB_BYTES;
        dequant_w<<<(N_DIM * (K_DIM / 8)) / 256, 256, 0, stream>>>(wp, wsc, wsB);
        conv_x<<<(M_DIM * (K_DIM / 8)) / 256, 256, 0, stream>>>(x, wsA);
        gemm_bf16_256<<<(M_DIM / 256) * (N_DIM / 256), 512, 0, stream>>>(wsA, wsB, bias, out);
    } else {
        dim3 grid(N_DIM / 128, M_DIM / 128);
        nvfp4_gemm<<<grid, 256, 0, stream>>>(x, wp, wsc, bias, out);
    }
}

// Round 13
// 297.339 us; speedup vs baseline: 1.7583x; 1.0240x over previous
//
#include <hip/hip_runtime.h>
#include <hip/hip_bf16.h>

typedef short bf16x8 __attribute__((ext_vector_type(8)));
typedef float f32x4 __attribute__((ext_vector_type(4)));

#define K_DIM 4096
#define N_DIM 16384
#define M_DIM 2048
#define STRIPE 16384                       // bytes per (tile128, kstep64) stripe in ws
#define TSTRIDE (64 * STRIPE)              // bytes per 128-row tile (1 MiB)
#define WSB_BYTES ((size_t)N_DIM * K_DIM * 2)   // 134217728
#define WSA_BYTES ((size_t)M_DIM * K_DIM * 2)   // 16777216

__device__ __forceinline__ unsigned f2bf(float f) {
    unsigned u = __builtin_bit_cast(unsigned, f);
    u += 0x7FFFu + ((u >> 16) & 1u);
    return u >> 16;   // RNE, inputs finite
}

// NVFP4 e2m1 nibble -> f32 (branchless), times scale
__device__ __forceinline__ float dec4(unsigned c, float s) {
    unsigned mag = c & 7u;
    unsigned u = (mag >= 2u) ? ((((mag >> 1) + 126u) << 23) | ((mag & 1u) << 22))
                             : (mag == 1u ? 0x3F000000u : 0u);
    u |= (c & 8u) << 28;   // sign
    return __builtin_bit_cast(float, u) * s;
}

// fast tanh-GELU (r12-verified): tanh(z) = (1-t)*rcp(1+t), t = 2^(-2*log2(e)*z).
__device__ __forceinline__ float fexp2(float x) {
    float r; asm("v_exp_f32 %0, %1" : "=v"(r) : "v"(x)); return r;
}
__device__ __forceinline__ float gelu_tanh(float v) {
    float c = v + 0.044715f * v * v * v;
    float x = fminf(-2.3022084f * c, 80.0f);   // -2*log2(e)*0.7978845608 * c
    float t = fexp2(x);
    float th = (1.0f - t) * __builtin_amdgcn_rcpf(1.0f + t);
    return 0.5f * v * (1.0f + th);
}

// ---------------- Pass 1a: dequant W -> bf16, tiled + pre-swizzled (verified) -----------
__global__ __launch_bounds__(256) void dequant_w(const int* __restrict__ wp,
                                                 const float* __restrict__ wsc,
                                                 unsigned char* __restrict__ dst) {
    int t = blockIdx.x * 256 + threadIdx.x;
    int n = t >> 9;
    int ck = t & 511;
    int kstep = ck >> 3, s = ck & 7;
    int nt = n >> 7, r = n & 127;

    const int4 p4 = *reinterpret_cast<const int4*>(wp + (size_t)n * (K_DIM / 2) + kstep * 32 + s * 4);
    float scale = wsc[(size_t)n * (K_DIM / 32) + kstep * 2 + (s >> 2)];

    const int pv[4] = {p4.x, p4.y, p4.z, p4.w};
    unsigned o[8];
    #pragma unroll
    for (int j = 0; j < 4; ++j) {
        unsigned b = (unsigned)pv[j] & 255u;
        o[2 * j]     = f2bf(dec4(b & 15u, scale));
        o[2 * j + 1] = f2bf(dec4((b >> 4) & 15u, scale));
    }
    uint4 v;
    v.x = o[0] | (o[1] << 16);
    v.y = o[2] | (o[3] << 16);
    v.z = o[4] | (o[5] << 16);
    v.w = o[6] | (o[7] << 16);

    size_t off = (size_t)(nt * 64 + kstep) * STRIPE
               + (size_t)r * 128 + (size_t)((s ^ (r & 7)) << 4);
    *reinterpret_cast<uint4*>(dst + off) = v;
}

// ---------------- Pass 1b: x f32 -> bf16, tiled + pre-swizzled (verified) ---------------
__global__ __launch_bounds__(256) void conv_x(const float* __restrict__ x,
                                              unsigned char* __restrict__ dst) {
    int t = blockIdx.x * 256 + threadIdx.x;
    int m = t >> 9;
    int ck = t & 511;
    int kstep = ck >> 3, s = ck & 7;
    int mt = m >> 7, r = m & 127;

    const float4* xp = reinterpret_cast<const float4*>(x + (size_t)m * K_DIM + kstep * 64 + s * 8);
    float4 a = xp[0], b = xp[1];
    uint4 v;
    v.x = f2bf(a.x) | (f2bf(a.y) << 16);
    v.y = f2bf(a.z) | (f2bf(a.w) << 16);
    v.z = f2bf(b.x) | (f2bf(b.y) << 16);
    v.w = f2bf(b.z) | (f2bf(b.w) << 16);

    size_t off = (size_t)(mt * 64 + kstep) * STRIPE
               + (size_t)r * 128 + (size_t)((s ^ (r & 7)) << 4);
    *reinterpret_cast<uint4*>(dst + off) = v;
}

// ---------------- Pass 2: 256^2 bf16 GEMM, ring-4, reg-prefetch, fast epilogue ----------
// r12 structure (248us, MfmaUtil 52%, conflicts 0) with two overlap edits:
//  (1) ka (A[4..7]) of tile t+1 is read at the END of tile t (after cluster 2 frees the
//      single ka buffer) -> both MFMA clusters fire with zero in-tile lgkm wait.
//  (2) setprio(1) around MFMA clusters (re-test at the new VALU balance).

__global__ __launch_bounds__(512, 2) void gemm_bf16_256(
    const unsigned char* __restrict__ wsA,
    const unsigned char* __restrict__ wsB,
    const float* __restrict__ bias,
    float* __restrict__ out)
{
    __shared__ unsigned char lds[131072];   // [0,64K) = A slots, [64K,128K) = B slots

    // XCD-chunked bijective swizzle
    int id = blockIdx.x;
    int wg = (id & 7) * 64 + (id >> 3);
    int MT = wg & 7;        // 0..7
    int NT = wg >> 3;       // 0..63

    const int tid  = threadIdx.x;
    const int lane = tid & 63;
    const int w    = tid >> 6;
    const int wm   = w >> 2;     // 0..1
    const int wn   = w & 3;      // 0..3
    const int fr   = lane & 15;  // fragment row
    const int fg   = lane >> 4;  // K-quarter 0..3

    const unsigned char* gA = wsA + (size_t)(2 * MT) * TSTRIDE;
    const unsigned char* gB = wsB + (size_t)(2 * NT) * TSTRIDE;

    // ds_read byte addresses (round-3 formulas, zero-conflict verified)
    int addrA[8];
    #pragma unroll
    for (int mi = 0; mi < 8; ++mi) {
        int row = wm * 128 + mi * 16 + fr;
        int L = row >> 1;
        addrA[mi] = L * 128 + (((((row & 1) << 2) | fg) ^ (L & 7)) << 4);
    }
    int addrB[4];
    #pragma unroll
    for (int ni = 0; ni < 4; ++ni) {
        int row = wn * 64 + ni * 16 + fr;
        int L = row >> 1;
        addrB[ni] = L * 128 + (((((row & 1) << 2) | fg) ^ (L & 7)) << 4);
    }

    // staging source offsets (round-3 version, matches the read layout above)
    int offST[2][2];
    #pragma unroll
    for (int j = 0; j < 2; ++j) {
        int c = w * 2 + j;
        int L = c * 8 + (lane >> 3);
        int p = lane & 7;
        int sl = p ^ (L & 7);
        int h = sl >> 2, fgs = sl & 3;
        int row = 2 * L + h;
        #pragma unroll
        for (int kb = 0; kb < 2; ++kb)
            offST[j][kb] = (row >> 7) * TSTRIDE + (row & 127) * 128
                         + ((((kb << 2) | fgs) ^ (row & 7)) << 4);
    }

#define GLDS(SRC, DOFF) __builtin_amdgcn_global_load_lds(                          \
        (const __attribute__((address_space(1))) unsigned int*)(SRC),              \
        (__attribute__((address_space(3))) unsigned int*)(&lds[DOFF]), 16, 0, 0)

#define STAGE_A(KSOFF, KB, SLOT) do {                                              \
        GLDS(gA + (KSOFF) + offST[0][KB], ((SLOT) << 14) + (w * 2 + 0) * 1024);    \
        GLDS(gA + (KSOFF) + offST[1][KB], ((SLOT) << 14) + (w * 2 + 1) * 1024);    \
    } while (0)
#define STAGE_B(KSOFF, KB, SLOT) do {                                              \
        GLDS(gB + (KSOFF) + offST[0][KB], 65536 + ((SLOT) << 14) + (w * 2 + 0) * 1024); \
        GLDS(gB + (KSOFF) + offST[1][KB], 65536 + ((SLOT) << 14) + (w * 2 + 1) * 1024); \
    } while (0)

// prefetch a tile's B[0..3] + A[0..3] fragments into named register arrays
#define READ_PF(PA, PB, SLOT) do {                                                 \
        const unsigned char* La_ = lds + ((SLOT) << 14);                           \
        const unsigned char* Lb_ = lds + 65536 + ((SLOT) << 14);                   \
        _Pragma("unroll") for (int ni = 0; ni < 4; ++ni)                           \
            PB[ni] = *reinterpret_cast<const bf16x8*>(Lb_ + addrB[ni]);            \
        _Pragma("unroll") for (int mi = 0; mi < 4; ++mi)                           \
            PA[mi] = *reinterpret_cast<const bf16x8*>(La_ + addrA[mi]);            \
    } while (0)

// read a tile's A[4..7] fragments into the (single-buffered) ka array
#define READ_KA(SLOT) do {                                                         \
        const unsigned char* Lk_ = lds + ((SLOT) << 14);                           \
        _Pragma("unroll") for (int mi = 0; mi < 4; ++mi)                           \
            ka[mi] = *reinterpret_cast<const bf16x8*>(Lk_ + addrA[4 + mi]);        \
    } while (0)

    f32x4 acc[8][4];
    #pragma unroll
    for (int mi = 0; mi < 8; ++mi)
        #pragma unroll
        for (int ni = 0; ni < 4; ++ni)
            acc[mi][ni] = (f32x4){0.f, 0.f, 0.f, 0.f};

    bf16x8 pa0[4], pb0[4], pa1[4], pb1[4];   // double-buffered prefetch fragments
    bf16x8 ka[4];                            // single-buffered A[4..7] (read 1 tile early)

    // prologue: stage tiles 0,1,2 into slots 0,1,2; wait tiles 0+1 (vmcnt(4)).
    STAGE_A(0, 0, 0);        STAGE_B(0, 0, 0);
    STAGE_A(0, 1, 1);        STAGE_B(0, 1, 1);
    STAGE_A(STRIPE, 0, 2);   STAGE_B(STRIPE, 0, 2);
    asm volatile("s_waitcnt vmcnt(4)" ::: "memory");
    __builtin_amdgcn_sched_barrier(0);
    __builtin_amdgcn_s_barrier();
    __builtin_amdgcn_sched_barrier(0);
    READ_PF(pa0, pb0, 0);
    READ_KA(0);

// one K-tile: both MFMA clusters fire from registers (pa/pb prefetched last tile,
// ka read at end of last tile); next tile's pa/pb read between clusters, its ka read
// after cluster 2; stage tile t+3; counted vmcnt (VMN<0 = last tile, no boundary).
#define TILE_BODY(RSLOT, NSLOT, PA, PB, NPA, NPB, DO_STG, STKS, STKB, SSLOT, DO_PF, VMN) do { \
        if (DO_STG) STAGE_A(STKS, STKB, SSLOT);                                    \
        __builtin_amdgcn_s_setprio(1);                                             \
        _Pragma("unroll") for (int mi = 0; mi < 4; ++mi)                           \
            _Pragma("unroll") for (int ni = 0; ni < 4; ++ni)                       \
                acc[mi][ni] = __builtin_amdgcn_mfma_f32_16x16x32_bf16(             \
                    PA[mi], PB[ni], acc[mi][ni], 0, 0, 0);                         \
        __builtin_amdgcn_s_setprio(0);                                             \
        if (DO_STG) STAGE_B(STKS, STKB, SSLOT);                                    \
        if (DO_PF) READ_PF(NPA, NPB, NSLOT);                                       \
        __builtin_amdgcn_s_setprio(1);                                             \
        _Pragma("unroll") for (int mi = 0; mi < 4; ++mi)                           \
            _Pragma("unroll") for (int ni = 0; ni < 4; ++ni)                       \
                acc[4 + mi][ni] = __builtin_amdgcn_mfma_f32_16x16x32_bf16(         \
                    ka[mi], PB[ni], acc[4 + mi][ni], 0, 0, 0);                     \
        __builtin_amdgcn_s_setprio(0);                                             \
        if (DO_PF) READ_KA(NSLOT);                                                 \
        if ((VMN) >= 0) {                                                          \
            if ((VMN) == 4)      asm volatile("s_waitcnt vmcnt(4)" ::: "memory");  \
            else                 asm volatile("s_waitcnt vmcnt(0)" ::: "memory");  \
            __builtin_amdgcn_sched_barrier(0);                                     \
            __builtin_amdgcn_s_barrier();                                          \
            __builtin_amdgcn_sched_barrier(0);                                     \
        }                                                                          \
    } while (0)

    // main loop: tiles t = 2tp, 2tp+1 for tp = 0..61; stage tile t+3; vmcnt(4) cadence.
    for (int tp = 0; tp < 62; ++tp) {
        const int scur = (tp & 1) << 1;              // slot of tile 2tp (0 or 2)
        const int ks1 = (tp + 1) * STRIPE;           // stage tile 2tp+3 (kb=1)
        const int ks2 = (tp + 2) * STRIPE;           // stage tile 2tp+4 (kb=0)
        TILE_BODY(scur,     scur ^ 1, pa0, pb0, pa1, pb1, 1, ks1, 1, scur ^ 3, 1, 4);
        TILE_BODY(scur ^ 1, scur ^ 2, pa1, pb1, pa0, pb0, 1, ks2, 0, scur,     1, 4);
    }
    // tail: tiles 124..127 in slots 0..3; stage only 127; drain 4 -> 0 -> 0.
    TILE_BODY(0, 1, pa0, pb0, pa1, pb1, 1, 63 * STRIPE, 1, 3, 1, 4);
    TILE_BODY(1, 2, pa1, pb1, pa0, pb0, 0, 0, 0, 0, 1, 0);
    TILE_BODY(2, 3, pa0, pb0, pa1, pb1, 0, 0, 0, 0, 1, 0);
    TILE_BODY(3, 0, pa1, pb1, pa0, pb0, 0, 0, 0, 0, 0, -1);

    // epilogue: bias + fast tanh-GELU, f32 stores (16x16 C/D layout: col=lane&15,
    // row = (lane>>4)*4 + reg).
    const int bm0 = MT * 256, bn0 = NT * 256;
    #pragma unroll
    for (int mi = 0; mi < 8; ++mi) {
        int row = bm0 + wm * 128 + mi * 16 + fg * 4;
        #pragma unroll
        for (int ni = 0; ni < 4; ++ni) {
            int col = bn0 + wn * 64 + ni * 16 + fr;
            float bv = bias[col];
            float* op = out + (size_t)row * N_DIM + col;
            #pragma unroll
            for (int q = 0; q < 4; ++q) {
                float v = acc[mi][ni][q] + bv;
                op[(size_t)q * N_DIM] = gelu_tanh(v);
            }
        }
    }
#undef TILE_BODY
#undef READ_KA
#undef READ_PF
#undef STAGE_A
#undef STAGE_B
#undef GLDS
}

// ---------------- Fallback: round-1 fused kernel (used only if ws too small) ------------
__global__ __launch_bounds__(256, 2) void nvfp4_gemm(
    const float* __restrict__ x,
    const int*   __restrict__ wp,
    const float* __restrict__ wscale,
    const float* __restrict__ bias,
    float* __restrict__ out)
{
    __shared__ uint4  lsA[128 * 8];
    __shared__ uint4  lsB[128 * 8];
    __shared__ float2 lut[256];

    const int tid = threadIdx.x;
    {
        static const float dectab[16] = {0.f, 0.5f, 1.f, 1.5f, 2.f, 3.f, 4.f, 6.f,
                                         -0.f,-0.5f,-1.f,-1.5f,-2.f,-3.f,-4.f,-6.f};
        lut[tid] = make_float2(dectab[tid & 15], dectab[(tid >> 4) & 15]);
    }

    const int bn0 = blockIdx.x * 128;
    const int bm0 = blockIdx.y * 128;
    const int r = tid >> 1;
    const int h = tid & 1;

    const float4* xp = reinterpret_cast<const float4*>(x + (size_t)(bm0 + r) * K_DIM) + h * 8;
    const uint4*  bp = reinterpret_cast<const uint4*>(wp + (size_t)(bn0 + r) * (K_DIM / 2)) + h * 4;
    const float*  sp = wscale + (size_t)(bn0 + r) * (K_DIM / 32) + h;

    float4 ax[8];
    uint4  bx[4];
    float  scale;
    #pragma unroll
    for (int j = 0; j < 8; ++j) ax[j] = xp[j];
    #pragma unroll
    for (int q = 0; q < 4; ++q) bx[q] = bp[q];
    scale = sp[0];

    f32x4 acc[4][4];
    #pragma unroll
    for (int mi = 0; mi < 4; ++mi)
        #pragma unroll
        for (int ni = 0; ni < 4; ++ni)
            acc[mi][ni] = (f32x4){0.f, 0.f, 0.f, 0.f};

    const int lane = tid & 63;
    const int wid  = tid >> 6;
    const int wm0  = (wid >> 1) * 64;
    const int wn0  = (wid & 1) * 64;
    const int fr   = lane & 15;
    const int fg   = lane >> 4;

    __syncthreads();

    for (int kt = 0; kt < 64; ++kt) {
        #pragma unroll
        for (int j = 0; j < 4; ++j) {
            float4 f0 = ax[2 * j], f1 = ax[2 * j + 1];
            uint4 v;
            v.x = f2bf(f0.x) | (f2bf(f0.y) << 16);
            v.y = f2bf(f0.z) | (f2bf(f0.w) << 16);
            v.z = f2bf(f1.x) | (f2bf(f1.y) << 16);
            v.w = f2bf(f1.z) | (f2bf(f1.w) << 16);
            lsA[(r * 8 + h * 4 + j) ^ (r & 7)] = v;
        }
        #pragma unroll
        for (int q = 0; q < 4; ++q) {
            uint4 p = bx[q];
            float2 d0 = lut[p.x & 255];
            float2 d1 = lut[p.y & 255];
            float2 d2 = lut[p.z & 255];
            float2 d3 = lut[p.w & 255];
            uint4 v;
            v.x = f2bf(d0.x * scale) | (f2bf(d0.y * scale) << 16);
            v.y = f2bf(d1.x * scale) | (f2bf(d1.y * scale) << 16);
            v.z = f2bf(d2.x * scale) | (f2bf(d2.y * scale) << 16);
            v.w = f2bf(d3.x * scale) | (f2bf(d3.y * scale) << 16);
            lsB[(r * 8 + h * 4 + q) ^ (r & 7)] = v;
        }
        __syncthreads();

        if (kt + 1 < 64) {
            #pragma unroll
            for (int j = 0; j < 8; ++j) ax[j] = xp[(kt + 1) * 16 + j];
            #pragma unroll
            for (int q = 0; q < 4; ++q) bx[q] = bp[(kt + 1) * 8 + q];
            scale = sp[(kt + 1) * 2];
        }

        #pragma unroll
        for (int kk = 0; kk < 2; ++kk) {
            bf16x8 af[4], bfr[4];
            #pragma unroll
            for (int mi = 0; mi < 4; ++mi) {
                int row = wm0 + mi * 16 + fr;
                af[mi] = __builtin_bit_cast(bf16x8, lsA[(row * 8 + kk * 4 + fg) ^ (row & 7)]);
            }
            #pragma unroll
            for (int ni = 0; ni < 4; ++ni) {
                int row = wn0 + ni * 16 + fr;
                bfr[ni] = __builtin_bit_cast(bf16x8, lsB[(row * 8 + kk * 4 + fg) ^ (row & 7)]);
            }
            #pragma unroll
            for (int mi = 0; mi < 4; ++mi)
                #pragma unroll
                for (int ni = 0; ni < 4; ++ni)
                    acc[mi][ni] = __builtin_amdgcn_mfma_f32_16x16x32_bf16(
                        af[mi], bfr[ni], acc[mi][ni], 0, 0, 0);
        }
        __syncthreads();
    }

    #pragma unroll
    for (int mi = 0; mi < 4; ++mi) {
        int row = bm0 + wm0 + mi * 16 + fg * 4;
        #pragma unroll
        for (int ni = 0; ni < 4; ++ni) {
            int col = bn0 + wn0 + ni * 16 + fr;
            float bv = bias[col];
            float* op = out + (size_t)row * N_DIM + col;
            #pragma unroll
            for (int q = 0; q < 4; ++q) {
                float v = acc[mi][ni][q] + bv;
                op[(size_t)q * N_DIM] = gelu_tanh(v);
            }
        }
    }
}

extern "C" void kernel_launch(void* const* d_in, const int* in_sizes, int n_in,
                              void* d_out, int out_size, void* d_ws, size_t ws_size,
                              hipStream_t stream) {
    const float* x    = (const float*)d_in[0];
    const int*   wp   = (const int*)d_in[1];
    const float* wsc  = (const float*)d_in[2];
    const float* bias = (const float*)d_in[3];
    float*       out  = (float*)d_out;
    (void)in_sizes; (void)n_in; (void)out_size;

    if (ws_size >= WSB_BYTES + WSA_BYTES) {
        unsigned char* wsB = (unsigned char*)d_ws;
        unsigned char* wsA = wsB + WSB_BYTES;
        dequant_w<<<(N_DIM * (K_DIM / 8)) / 256, 256, 0, stream>>>(wp, wsc, wsB);
        conv_x<<<(M_DIM * (K_DIM / 8)) / 256, 256, 0, stream>>>(x, wsA);
        gemm_bf16_256<<<(M_DIM / 256) * (N_DIM / 256), 512, 0, stream>>>(wsA, wsB, bias, out);
    } else {
        dim3 grid(N_DIM / 128, M_DIM / 128);
        nvfp4_gemm<<<grid, 256, 0, stream>>>(x, wp, wsc, bias, out);
    }
}